// Round 7
// baseline (346.039 us; speedup 1.0000x reference)
//
#include <hip/hip_runtime.h>

typedef unsigned short ushortb;
typedef __attribute__((ext_vector_type(8))) short short8;    // 8 bf16 = 16B (MFMA A/B frag)
typedef __attribute__((ext_vector_type(4))) float f32x4;     // MFMA C/D frag

__device__ __forceinline__ ushortb f2bb(float f) {
    union { float f; unsigned u; } x; x.f = f;
    unsigned r = x.u + 0x7fffu + ((x.u >> 16) & 1u);   // RNE
    return (ushortb)(r >> 16);
}
__device__ __forceinline__ float bb2f(ushortb u) {
    union { unsigned u; float f; } x; x.u = ((unsigned)u) << 16; return x.f;
}

// packed fp32x2 -> bf16x2 (low|high), RNE. gfx950 v_cvt_pk_bf16_f32 if available.
__device__ __forceinline__ unsigned pkbb(float a, float b) {
#if __has_builtin(__builtin_amdgcn_cvt_pk_bf16_f32)
    auto p = __builtin_amdgcn_cvt_pk_bf16_f32(a, b);
    unsigned u; __builtin_memcpy(&u, &p, 4);
    return u;
#else
    return (unsigned)f2bb(a) | ((unsigned)f2bb(b) << 16);
#endif
}

#if __has_builtin(__builtin_amdgcn_exp2f)
#define EXP2(x) __builtin_amdgcn_exp2f(x)
#else
#define EXP2(x) exp2f(x)
#endif

// async global->LDS DMA, 16B/lane; lds base wave-uniform, lane -> base+lane*16
__device__ __forceinline__ void async_ld16(void* lds, const void* g) {
    __builtin_amdgcn_global_load_lds(
        (const __attribute__((address_space(1))) void*)g,
        (__attribute__((address_space(3))) void*)lds, 16, 0, 0);
}

// ---------------------------------------------------------------------------
#define EP_EMB       0   // + bias + pe table
#define EP_RES       2   // + bf16 residual
#define EP_BIAS_RELU 3   // + bias, relu
#define EP_BIAS_RES  4   // + bias + bf16 residual
#define EP_QKV       7   // N=1536 fused: cols<1024 -> Qb/Kb, cols>=1024 -> Vt transposed

// C[M,N] = A[M,K] @ Bt[N,K]^T (+ epilogue). bf16 in, fp32 MFMA accum, bf16 out.
// Block 256 thr (4 waves 2x2), tile 128x128, BK=64, double-buffered
// global_load_lds staging; XOR-swizzled unpadded LDS. 64 KB LDS -> 2 blk/CU
// (cross-block overlap hides the per-tile barrier drain -- m114).
template <int EP>
__global__ __launch_bounds__(256) void gemm_mfma(
    const ushortb* __restrict__ A, const ushortb* __restrict__ Bt,
    const float* __restrict__ bias, const ushortb* __restrict__ res,
    const float* __restrict__ pe, ushortb* __restrict__ C,
    int M, int N, int K)
{
    __shared__ ushortb sA[2][128][64];   // 32 KB
    __shared__ ushortb sB[2][128][64];   // 32 KB

    const int tid = threadIdx.x;
    const int wave = tid >> 6, lane = tid & 63;
    const int quad = lane >> 4, l15 = lane & 15;
    const int row0 = blockIdx.x * 128;
    const int col0 = blockIdx.y * 128;
    const int wm = (wave >> 1) * 64, wn = (wave & 1) * 64;
    const int srl = lane >> 3, slot = lane & 7;

    f32x4 acc[4][4];
    #pragma unroll
    for (int i = 0; i < 4; ++i)
        #pragma unroll
        for (int j = 0; j < 4; ++j) acc[i][j] = (f32x4){0.f, 0.f, 0.f, 0.f};

    // initial stage -> buffer 0
    #pragma unroll
    for (int c = 0; c < 4; ++c) {
        int rbase = wave * 32 + c * 8;
        int r = rbase + srl;
        int ka = (slot ^ ((r ^ (r >> 3)) & 7)) * 8;
        async_ld16(&sA[0][rbase][0], A  + (size_t)(row0 + r) * K + ka);
        async_ld16(&sB[0][rbase][0], Bt + (size_t)(col0 + r) * K + ka);
    }

    int buf = 0;
    for (int k0 = 0; k0 < K; k0 += 64) {
        __syncthreads();   // drains DMA for 'buf' + prev compute
        if (k0 + 64 < K) {
            int nb = buf ^ 1;
            #pragma unroll
            for (int c = 0; c < 4; ++c) {
                int rbase = wave * 32 + c * 8;
                int r = rbase + srl;
                int ka = (slot ^ ((r ^ (r >> 3)) & 7)) * 8;
                async_ld16(&sA[nb][rbase][0], A  + (size_t)(row0 + r) * K + k0 + 64 + ka);
                async_ld16(&sB[nb][rbase][0], Bt + (size_t)(col0 + r) * K + k0 + 64 + ka);
            }
        }
        #pragma unroll
        for (int kc = 0; kc < 2; ++kc) {
            short8 af[4], bf[4];
            #pragma unroll
            for (int i = 0; i < 4; ++i) {
                int m = wm + i * 16 + l15;
                af[i] = *(const short8*)&sA[buf][m][(((kc * 4 + quad) ^ ((m ^ (m >> 3)) & 7))) * 8];
            }
            #pragma unroll
            for (int j = 0; j < 4; ++j) {
                int n = wn + j * 16 + l15;
                bf[j] = *(const short8*)&sB[buf][n][(((kc * 4 + quad) ^ ((n ^ (n >> 3)) & 7))) * 8];
            }
            #pragma unroll
            for (int i = 0; i < 4; ++i)
                #pragma unroll
                for (int j = 0; j < 4; ++j)
                    acc[i][j] = __builtin_amdgcn_mfma_f32_16x16x32_bf16(af[i], bf[j], acc[i][j], 0, 0, 0);
        }
        buf ^= 1;
    }

    if constexpr (EP == EP_QKV) {
        if (col0 < 1024) {
            ushortb* dst = C + ((size_t)(col0 >> 9)) * ((size_t)M * 512);
            #pragma unroll
            for (int i = 0; i < 4; ++i)
                #pragma unroll
                for (int r = 0; r < 4; ++r) {
                    int row = row0 + wm + i * 16 + quad * 4 + r;
                    #pragma unroll
                    for (int j = 0; j < 4; ++j) {
                        int col = (col0 + wn + j * 16 + l15) & 511;
                        dst[(size_t)row * 512 + col] = f2bb(acc[i][j][r]);
                    }
                }
        } else {
            ushortb* Vt = C + (size_t)2 * M * 512;
            int bb_ = row0 >> 10;
            #pragma unroll
            for (int i = 0; i < 4; ++i) {
                int s = (row0 & 1023) + wm + i * 16 + quad * 4;
                #pragma unroll
                for (int j = 0; j < 4; ++j) {
                    int vcol = col0 + wn + j * 16 + l15 - 1024;
                    int h = vcol >> 7, e = vcol & 127;
                    uint2 v;
                    v.x = pkbb(acc[i][j][0], acc[i][j][1]);
                    v.y = pkbb(acc[i][j][2], acc[i][j][3]);
                    *(uint2*)&Vt[((size_t)((bb_ * 4 + h) * 128 + e) << 10) + s] = v;
                }
            }
        }
        return;
    }

    #pragma unroll
    for (int i = 0; i < 4; ++i) {
        #pragma unroll
        for (int r = 0; r < 4; ++r) {
            int row = row0 + wm + i * 16 + quad * 4 + r;
            #pragma unroll
            for (int j = 0; j < 4; ++j) {
                int col = col0 + wn + j * 16 + l15;
                float v = acc[i][j][r];
                if constexpr (EP == EP_EMB) {
                    v += bias[col] + pe[((row & 1023) << 9) + col];
                } else if constexpr (EP == EP_RES) {
                    v += bb2f(res[(size_t)row * N + col]);
                } else if constexpr (EP == EP_BIAS_RELU) {
                    v = fmaxf(v + bias[col], 0.0f);
                } else if constexpr (EP == EP_BIAS_RES) {
                    v += bias[col] + bb2f(res[(size_t)row * N + col]);
                }
                C[(size_t)row * N + col] = f2bb(v);
            }
        }
    }
}

// ---------------------------------------------------------------------------
// 256x256-tile GEMM, BK=64, 2-phase __syncthreads structure, 128 KB LDS
// (1 blk/CU; 256^2 wave tile needs >128 VGPR so 2 blk/CU is infeasible --
// round-5 spill disaster). 512 thr (8 waves, 2M x 4N), wave tile 128x64.
// 0.375 ds_read/MFMA vs 0.5 on the 128^2 tile. Bias+ReLU epilogue (FFN1).
__global__ __launch_bounds__(512, 2) void gemm_256(
    const ushortb* __restrict__ A, const ushortb* __restrict__ Bt,
    const float* __restrict__ bias, ushortb* __restrict__ C,
    int M, int N, int K)
{
    __shared__ ushortb sA[2][256][64];   // 64 KB
    __shared__ ushortb sB[2][256][64];   // 64 KB

    const int tid = threadIdx.x;
    const int wave = tid >> 6, lane = tid & 63;
    const int quad = lane >> 4, l15 = lane & 15;
    const int row0 = blockIdx.x * 256;
    const int col0 = blockIdx.y * 256;
    const int wm = (wave >> 2) * 128;    // 2 row groups of 128
    const int wn = (wave & 3) * 64;      // 4 col groups of 64
    const int srl = lane >> 3, slot = lane & 7;

    f32x4 acc[8][4];
    #pragma unroll
    for (int i = 0; i < 8; ++i)
        #pragma unroll
        for (int j = 0; j < 4; ++j) acc[i][j] = (f32x4){0.f, 0.f, 0.f, 0.f};

    // initial stage -> buffer 0 (per wave: rows wave*32..wave*32+31 of A and B)
    #pragma unroll
    for (int c = 0; c < 4; ++c) {
        int rbase = wave * 32 + c * 8;
        int r = rbase + srl;
        int ka = (slot ^ ((r ^ (r >> 3)) & 7)) * 8;
        async_ld16(&sA[0][rbase][0], A  + (size_t)(row0 + r) * K + ka);
        async_ld16(&sB[0][rbase][0], Bt + (size_t)(col0 + r) * K + ka);
    }

    int buf = 0;
    for (int k0 = 0; k0 < K; k0 += 64) {
        __syncthreads();   // drains DMA for 'buf' + prev compute
        if (k0 + 64 < K) {
            int nb = buf ^ 1;
            #pragma unroll
            for (int c = 0; c < 4; ++c) {
                int rbase = wave * 32 + c * 8;
                int r = rbase + srl;
                int ka = (slot ^ ((r ^ (r >> 3)) & 7)) * 8;
                async_ld16(&sA[nb][rbase][0], A  + (size_t)(row0 + r) * K + k0 + 64 + ka);
                async_ld16(&sB[nb][rbase][0], Bt + (size_t)(col0 + r) * K + k0 + 64 + ka);
            }
        }
        #pragma unroll
        for (int kc = 0; kc < 2; ++kc) {
            short8 af[8], bf[4];
            #pragma unroll
            for (int i = 0; i < 8; ++i) {
                int m = wm + i * 16 + l15;
                af[i] = *(const short8*)&sA[buf][m][(((kc * 4 + quad) ^ ((m ^ (m >> 3)) & 7))) * 8];
            }
            #pragma unroll
            for (int j = 0; j < 4; ++j) {
                int n = wn + j * 16 + l15;
                bf[j] = *(const short8*)&sB[buf][n][(((kc * 4 + quad) ^ ((n ^ (n >> 3)) & 7))) * 8];
            }
            #pragma unroll
            for (int i = 0; i < 8; ++i)
                #pragma unroll
                for (int j = 0; j < 4; ++j)
                    acc[i][j] = __builtin_amdgcn_mfma_f32_16x16x32_bf16(af[i], bf[j], acc[i][j], 0, 0, 0);
        }
        buf ^= 1;
    }

    #pragma unroll
    for (int i = 0; i < 8; ++i) {
        #pragma unroll
        for (int r = 0; r < 4; ++r) {
            int row = row0 + wm + i * 16 + quad * 4 + r;
            #pragma unroll
            for (int j = 0; j < 4; ++j) {
                int col = col0 + wn + j * 16 + l15;
                float v = fmaxf(acc[i][j][r] + bias[col], 0.0f);
                C[(size_t)row * N + col] = f2bb(v);
            }
        }
    }
}

// ---------------------------------------------------------------------------
// Merged prep kernel: all six independent prep stages in one dispatch over a
// partitioned 1D grid (block-uniform branch). Saves launch gaps + tails.
// Block 8192 additionally zeros the zbuf accumulators + done-counter (33 u32).
//   [0,8192)        conv_x: x fp32 -> xb bf16 (4 elems/thread)
//   [8192,10240)    pe table fp32 [1024][512]
//   [10240,10368)   pairT512: emb_w (z=0) / WO (z=1) transpose, 8x8x2
//   [10368,10560)   qkvT: WQ/WK/WV [512][128] -> wqkvt rows, 2x8x12, Q scaled
//   [10560,10816)   tileT l1w [512][2048] -> l1wt, 32x8
//   [10816,11072)   tileT l2w [2048][512] -> l2wt, 8x32
__global__ __launch_bounds__(256) void prep_all(
    const float* __restrict__ x, ushortb* __restrict__ xb,
    float* __restrict__ pe,
    const float* __restrict__ emb_w, const float* __restrict__ WO,
    ushortb* __restrict__ embwt, ushortb* __restrict__ wot,
    const float* __restrict__ WQ, const float* __restrict__ WK,
    const float* __restrict__ WV, ushortb* __restrict__ wqkvt, float qscale,
    const float* __restrict__ l1w, ushortb* __restrict__ l1wt,
    const float* __restrict__ l2w, ushortb* __restrict__ l2wt,
    unsigned* __restrict__ zinit)
{
    __shared__ float t[64][65];
    const int bid = blockIdx.x;
    const int tid = threadIdx.x;

    if (bid < 8192) {                       // conv_x
        size_t i4 = (size_t)bid * 256 + tid;
        float4 v = *(const float4*)(x + i4 * 4);
        ushort4 o;
        o.x = f2bb(v.x); o.y = f2bb(v.y); o.z = f2bb(v.z); o.w = f2bb(v.w);
        *(ushort4*)(xb + i4 * 4) = o;
        return;
    }
    if (bid < 10240) {                      // pe table (+ zbuf/counter zero)
        if (bid == 8192 && tid < 33) zinit[tid] = 0u;
        int idx = (bid - 8192) * 256 + tid;  // s*512 + c
        int s = idx >> 9, c = idx & 511;
        float div = expf((float)(c & ~1) * (-9.210340371976184f / 512.0f));
        float ang = (float)s * div;
        pe[idx] = (c & 1) ? cosf(ang) : sinf(ang);
        return;
    }

    const int tx = tid & 63, ty = tid >> 6;

    if (bid < 10368) {                      // pairT512 (8x8x2)
        int b2 = bid - 10240;
        int c0 = (b2 & 7) * 64, r0 = ((b2 >> 3) & 7) * 64, z = b2 >> 6;
        const float* in = z ? WO : emb_w;
        ushortb* out = z ? wot : embwt;
        #pragma unroll
        for (int i = 0; i < 16; ++i) {
            int r = ty + i * 4;
            t[r][tx] = in[(size_t)(r0 + r) * 512 + c0 + tx];
        }
        __syncthreads();
        #pragma unroll
        for (int i = 0; i < 16; ++i) {
            int r = ty + i * 4;
            out[(size_t)(c0 + r) * 512 + r0 + tx] = f2bb(t[tx][r]);
        }
        return;
    }
    if (bid < 10560) {                      // qkvT (2x8x12)
        int b3 = bid - 10368;
        int c0 = (b3 & 1) * 64, r0 = ((b3 >> 1) & 7) * 64, z = b3 >> 4;
        int sel = z >> 2, zz = z & 3;
        const float* in = (sel == 0 ? WQ : (sel == 1 ? WK : WV)) + (size_t)zz * 65536;
        ushortb* out = wqkvt + (size_t)sel * 262144 + (size_t)zz * 65536;
        const float scale = (sel == 0) ? qscale : 1.0f;
        #pragma unroll
        for (int i = 0; i < 16; ++i) {
            int r = ty + i * 4;
            t[r][tx] = in[(size_t)(r0 + r) * 128 + c0 + tx] * scale;
        }
        __syncthreads();
        #pragma unroll
        for (int i = 0; i < 16; ++i) {
            int r = ty + i * 4;
            out[(size_t)(c0 + r) * 512 + r0 + tx] = f2bb(t[tx][r]);
        }
        return;
    }
    if (bid < 10816) {                      // tileT l1w: [512][2048] -> [2048][512]
        int b4 = bid - 10560;
        int c0 = (b4 & 31) * 64, r0 = (b4 >> 5) * 64;
        #pragma unroll
        for (int i = 0; i < 16; ++i) {
            int r = ty + i * 4;
            t[r][tx] = l1w[(size_t)(r0 + r) * 2048 + c0 + tx];
        }
        __syncthreads();
        #pragma unroll
        for (int i = 0; i < 16; ++i) {
            int r = ty + i * 4;
            l1wt[(size_t)(c0 + r) * 512 + r0 + tx] = f2bb(t[tx][r]);
        }
        return;
    }
    {                                       // tileT l2w: [2048][512] -> [512][2048]
        int b5 = bid - 10816;
        int c0 = (b5 & 7) * 64, r0 = (b5 >> 3) * 64;
        #pragma unroll
        for (int i = 0; i < 16; ++i) {
            int r = ty + i * 4;
            t[r][tx] = l2w[(size_t)(r0 + r) * 512 + c0 + tx];
        }
        __syncthreads();
        #pragma unroll
        for (int i = 0; i < 16; ++i) {
            int r = ty + i * 4;
            l2wt[(size_t)(c0 + r) * 2048 + r0 + tx] = f2bb(t[tx][r]);
        }
        return;
    }
}

// ---------------------------------------------------------------------------
// MFMA flash attention, fixed-max softmax, double-buffered DMA K/V staging,
// XCD-local grid, packed bf16 conversions. Q pre-scaled by log2(e)/sqrt(128).
// Round-0 structure (__syncthreads double-buffer) with PAIRED staging (16
// barrier drains instead of 32) + s_setprio(1) around MFMA clusters (m191:
// attn-positive; blocks are independent so waves sit at different phases).
__global__ __launch_bounds__(256) void attn_mfma(
    const ushortb* __restrict__ Qb, const ushortb* __restrict__ Kb,
    const ushortb* __restrict__ Vt, ushortb* __restrict__ O)
{
    __shared__ ushortb sK[2][2][32][128];    // 32 KB
    __shared__ ushortb sVt[2][2][128][32];   // 32 KB
    __shared__ ushortb sP[4][32][40];        // 10 KB, [wave][q_local][t]

    const int tid = threadIdx.x;
    const int wave = tid >> 6, lane = tid & 63;
    const int quad = lane >> 4, l15 = lane & 15;
    const int bid = blockIdx.x;          // XCD swizzle: same (b,h) -> ids 64 apart
    const int bh = bid & 63, qc = bid >> 6;
    const int b = bh >> 2, h = bh & 3;
    const int q0 = qc * 128 + wave * 32;
    const size_t qk_off = ((size_t)b << 10) * 512 + h * 128;
    const ushortb* Qp = Qb + qk_off;
    const ushortb* Kp = Kb + qk_off;
    const ushortb* Vp = Vt + (((size_t)(b * 4 + h)) << 17);

    short8 qfA[4], qfB[4];   // B-frags: Q[q=l15 | 16+l15][k=quad*8+j]
    {
        const ushortb* qa = Qp + (size_t)(q0 + l15) * 512;
        const ushortb* qb = Qp + (size_t)(q0 + 16 + l15) * 512;
        #pragma unroll
        for (int kc = 0; kc < 4; ++kc) {
            qfA[kc] = *(const short8*)(qa + kc * 32 + quad * 8);
            qfB[kc] = *(const short8*)(qb + kc * 32 + quad * 8);
        }
    }

    f32x4 oA[8], oB[8];
    #pragma unroll
    for (int dt = 0; dt < 8; ++dt) {
        oA[dt] = (f32x4){0.f, 0.f, 0.f, 0.f};
        oB[dt] = (f32x4){0.f, 0.f, 0.f, 0.f};
    }
    float lA = 0.f, lB = 0.f;

    // initial stage: pair of tiles (t=0,32) -> buffer 0
    #pragma unroll
    for (int s = 0; s < 2; ++s) {
        #pragma unroll
        for (int c = 0; c < 2; ++c) {
            int seg = wave * 2 + c;
            int rk = seg * 4 + (lane >> 4);
            int ck = (lane & 15) ^ (rk & 15);
            async_ld16(&sK[0][s][seg * 4][0], Kp + (size_t)(s * 32 + rk) * 512 + ck * 8);
            int dv = seg * 16 + (lane >> 2);
            int cv = (lane & 3) ^ (dv & 3);
            async_ld16(&sVt[0][s][seg * 16][0], Vp + ((size_t)dv << 10) + s * 32 + cv * 8);
        }
    }

    int buf = 0;
    for (int t0 = 0; t0 < 1024; t0 += 64) {
        __syncthreads();   // DMA for 'buf' (both subs) complete + prev compute done
        if (t0 + 64 < 1024) {
            int nb = buf ^ 1;
            #pragma unroll
            for (int s = 0; s < 2; ++s) {
                #pragma unroll
                for (int c = 0; c < 2; ++c) {
                    int seg = wave * 2 + c;
                    int rk = seg * 4 + (lane >> 4);
                    int ck = (lane & 15) ^ (rk & 15);
                    async_ld16(&sK[nb][s][seg * 4][0],
                               Kp + (size_t)(t0 + 64 + s * 32 + rk) * 512 + ck * 8);
                    int dv = seg * 16 + (lane >> 2);
                    int cv = (lane & 3) ^ (dv & 3);
                    async_ld16(&sVt[nb][s][seg * 16][0],
                               Vp + ((size_t)dv << 10) + t0 + 64 + s * 32 + cv * 8);
                }
            }
        }

        #pragma unroll
        for (int sub = 0; sub < 2; ++sub) {
            // S^T: D[t][q]; t = quad*4+reg (+0/16), q = l15 (A-group) / 16+l15 (B)
            f32x4 sA0 = {0,0,0,0}, sA1 = {0,0,0,0}, sB0 = {0,0,0,0}, sB1 = {0,0,0,0};
            __builtin_amdgcn_s_setprio(1);
            #pragma unroll
            for (int kc = 0; kc < 4; ++kc) {
                short8 k0f = *(const short8*)&sK[buf][sub][l15][((kc * 4 + quad) ^ l15) * 8];
                short8 k1f = *(const short8*)&sK[buf][sub][16 + l15][((kc * 4 + quad) ^ l15) * 8];
                sA0 = __builtin_amdgcn_mfma_f32_16x16x32_bf16(k0f, qfA[kc], sA0, 0, 0, 0);
                sA1 = __builtin_amdgcn_mfma_f32_16x16x32_bf16(k1f, qfA[kc], sA1, 0, 0, 0);
                sB0 = __builtin_amdgcn_mfma_f32_16x16x32_bf16(k0f, qfB[kc], sB0, 0, 0, 0);
                sB1 = __builtin_amdgcn_mfma_f32_16x16x32_bf16(k1f, qfB[kc], sB1, 0, 0, 0);
            }
            __builtin_amdgcn_s_setprio(0);

            // fixed-max softmax: p = 2^score (log2e baked into Q scale)
            float pA0[4], pA1[4], pB0[4], pB1[4];
            float sumA = 0.f, sumB = 0.f;
            #pragma unroll
            for (int r = 0; r < 4; ++r) {
                pA0[r] = EXP2(sA0[r]); pA1[r] = EXP2(sA1[r]);
                pB0[r] = EXP2(sB0[r]); pB1[r] = EXP2(sB1[r]);
                sumA += pA0[r] + pA1[r];
                sumB += pB0[r] + pB1[r];
            }
            lA += sumA; lB += sumB;

            // store P[q][t] bf16 via packed converts (2 x uint2 per q-row half)
            uint2 w;
            w.x = pkbb(pA0[0], pA0[1]); w.y = pkbb(pA0[2], pA0[3]);
            *(uint2*)&sP[wave][l15][quad * 4] = w;
            w.x = pkbb(pA1[0], pA1[1]); w.y = pkbb(pA1[2], pA1[3]);
            *(uint2*)&sP[wave][l15][16 + quad * 4] = w;
            w.x = pkbb(pB0[0], pB0[1]); w.y = pkbb(pB0[2], pB0[3]);
            *(uint2*)&sP[wave][16 + l15][quad * 4] = w;
            w.x = pkbb(pB1[0], pB1[1]); w.y = pkbb(pB1[2], pB1[3]);
            *(uint2*)&sP[wave][16 + l15][16 + quad * 4] = w;

            short8 pfA = *(const short8*)&sP[wave][l15][quad * 8];
            short8 pfB = *(const short8*)&sP[wave][16 + l15][quad * 8];

            __builtin_amdgcn_s_setprio(1);
            #pragma unroll
            for (int dt = 0; dt < 8; ++dt) {
                int d = dt * 16 + l15;
                short8 vfrag = *(const short8*)&sVt[buf][sub][d][(quad ^ (d & 3)) * 8];
                oA[dt] = __builtin_amdgcn_mfma_f32_16x16x32_bf16(pfA, vfrag, oA[dt], 0, 0, 0);
                oB[dt] = __builtin_amdgcn_mfma_f32_16x16x32_bf16(pfB, vfrag, oB[dt], 0, 0, 0);
            }
            __builtin_amdgcn_s_setprio(0);
        }
        buf ^= 1;
    }

    lA += __shfl_xor(lA, 16); lA += __shfl_xor(lA, 32);
    lB += __shfl_xor(lB, 16); lB += __shfl_xor(lB, 32);

    const size_t obase = (((size_t)(b * 4 + h) << 10) + q0) << 7;
    #pragma unroll
    for (int r = 0; r < 4; ++r) {
        float invA = 1.0f / __shfl(lA, quad * 4 + r);
        float invB = 1.0f / __shfl(lB, quad * 4 + r);
        int qa = quad * 4 + r, qb = 16 + quad * 4 + r;
        #pragma unroll
        for (int dt = 0; dt < 8; ++dt) {
            O[obase + ((size_t)qa << 7) + dt * 16 + l15] = f2bb(oA[dt][r] * invA);
            O[obase + ((size_t)qb << 7) + dt * 16 + l15] = f2bb(oB[dt][r] * invB);
        }
    }
}

// ---------------------------------------------------------------------------
// LayerNorm over 512 features: wave per row, 8 elems/lane, shuffle reduce.
__global__ __launch_bounds__(256) void ln_kernel(const ushortb* __restrict__ in,
                                                 const float* __restrict__ g,
                                                 const float* __restrict__ bta,
                                                 ushortb* __restrict__ out)
{
    const int lane = threadIdx.x & 63, w = threadIdx.x >> 6;
    const size_t row = (size_t)blockIdx.x * 4 + w;
    const int e0 = lane * 8;
    short8 v8 = *(const short8*)(in + row * 512 + e0);
    float v[8];
    #pragma unroll
    for (int k = 0; k < 8; ++k) v[k] = bb2f((ushortb)((short*)&v8)[k]);
    float s = 0.f, sq = 0.f;
    #pragma unroll
    for (int k = 0; k < 8; ++k) { s += v[k]; sq += v[k] * v[k]; }
    #pragma unroll
    for (int o = 1; o < 64; o <<= 1) { s += __shfl_xor(s, o); sq += __shfl_xor(sq, o); }
    float mu = s * (1.0f / 512.0f);
    float var = sq * (1.0f / 512.0f) - mu * mu;
    float rstd = rsqrtf(var + 1e-5f);
    float4 g0 = *(const float4*)(g + e0),  g1 = *(const float4*)(g + e0 + 4);
    float4 b0 = *(const float4*)(bta + e0), b1 = *(const float4*)(bta + e0 + 4);
    float gg[8] = {g0.x, g0.y, g0.z, g0.w, g1.x, g1.y, g1.z, g1.w};
    float bb[8] = {b0.x, b0.y, b0.z, b0.w, b1.x, b1.y, b1.z, b1.w};
    short8 o8;
    #pragma unroll
    for (int k = 0; k < 8; ++k)
        ((short*)&o8)[k] = (short)f2bb((v[k] - mu) * rstd * gg[k] + bb[k]);
    *(short8*)(out + row * 512 + e0) = o8;
}

// ---------------------------------------------------------------------------
// MaxPool1d(16) + FC[32768,2] + log_softmax fused: grid (16 batch, 16 chunks),
// atomicAdd partials into zbuf; last block (device-scope ticket) computes the
// logits. done counter sits at zbuf+32 (both zeroed by prep_all each run).
__global__ __launch_bounds__(256) void final_fused(const ushortb* __restrict__ ln2,
                                                   const float* __restrict__ fcw,
                                                   const float* __restrict__ fcb,
                                                   float* __restrict__ zbuf,
                                                   unsigned* __restrict__ done,
                                                   float* __restrict__ out)
{
    const int b = blockIdx.x, chunk = blockIdx.y;
    const int tid = threadIdx.x;
    float a0 = 0.0f, a1 = 0.0f;
    #pragma unroll
    for (int t = 0; t < 8; ++t) {
        int m = chunk * 2048 + t * 256 + tid;
        int s = m >> 5, j = m & 31;
        const ushortb* p = ln2 + (((size_t)(b * 1024 + s)) << 9) + j * 16;
        float mx = -1e30f;
        #pragma unroll
        for (int e = 0; e < 16; ++e) mx = fmaxf(mx, bb2f(p[e]));
        a0 += mx * fcw[2 * m];
        a1 += mx * fcw[2 * m + 1];
    }
    __shared__ float r0[256], r1[256];
    __shared__ unsigned lastf;
    r0[tid] = a0; r1[tid] = a1;
    __syncthreads();
    for (int o = 128; o > 0; o >>= 1) {
        if (tid < o) { r0[tid] += r0[tid + o]; r1[tid] += r1[tid + o]; }
        __syncthreads();
    }
    if (tid == 0) {
        atomicAdd(&zbuf[2 * b],     r0[0]);
        atomicAdd(&zbuf[2 * b + 1], r1[0]);
        __threadfence();                       // order partials before ticket
        lastf = (atomicAdd(done, 1u) == 255u); // 256 blocks total
    }
    __syncthreads();
    if (lastf && tid < 16) {
        __threadfence();
        // coherent reads of all partials via device-scope atomic no-ops
        float z0 = atomicAdd(&zbuf[2 * tid], 0.0f)     + fcb[0];
        float z1 = atomicAdd(&zbuf[2 * tid + 1], 0.0f) + fcb[1];
        float mx = fmaxf(z0, z1);
        float lse = mx + logf(expf(z0 - mx) + expf(z1 - mx));
        out[2 * tid]     = z0 - lse;
        out[2 * tid + 1] = z1 - lse;
    }
}

// ---------------------------------------------------------------------------
extern "C" void kernel_launch(void* const* d_in, const int* in_sizes, int n_in,
                              void* d_out, int out_size, void* d_ws, size_t ws_size,
                              hipStream_t stream)
{
    const float* x     = (const float*)d_in[0];
    const float* emb_w = (const float*)d_in[1];
    const float* emb_b = (const float*)d_in[2];
    const float* WQ    = (const float*)d_in[3];
    const float* WK    = (const float*)d_in[4];
    const float* WV    = (const float*)d_in[5];
    const float* WO    = (const float*)d_in[6];
    const float* g1    = (const float*)d_in[7];
    const float* b1    = (const float*)d_in[8];
    const float* l1w   = (const float*)d_in[9];
    const float* l1b   = (const float*)d_in[10];
    const float* l2w   = (const float*)d_in[11];
    const float* l2b   = (const float*)d_in[12];
    const float* g2    = (const float*)d_in[13];
    const float* b2    = (const float*)d_in[14];
    const float* fcw   = (const float*)d_in[15];
    const float* fcb   = (const float*)d_in[16];
    float* out = (float*)d_out;

    char* ws = (char*)d_ws;
    const size_t Ub = (size_t)16384 * 512 * 2;   // 16.78 MB bf16 activation unit
    // u0: xb -> r1 -> r2   u1: h0b -> ln2   u2: Qb -> ln1
    // u3: Kb -> mid[0]     u4: Vt -> mid[1] u5: headR -> mid[2]  u6: mid[3]
    ushortb* xb    = (ushortb*)(ws + 0 * Ub);
    ushortb* h0b   = (ushortb*)(ws + 1 * Ub);
    ushortb* Qb    = (ushortb*)(ws + 2 * Ub);   // Kb = Qb + M*512, Vt = Qb + 2*M*512
    ushortb* Kb    = (ushortb*)(ws + 3 * Ub);
    ushortb* Vt    = (ushortb*)(ws + 4 * Ub);
    ushortb* headR = (ushortb*)(ws + 5 * Ub);
    ushortb* mid   = (ushortb*)(ws + 3 * Ub);   // [16384,2048] over u3..u6
    ushortb* r1    = xb;
    ushortb* ln1   = Qb;
    ushortb* r2    = xb;
    ushortb* ln2   = h0b;
    char* wb = ws + 7 * Ub;
    ushortb* embwt = (ushortb*)(wb);                        // [512][512]
    ushortb* wqkvt = (ushortb*)(wb + 524288);               // [1536][512]
    ushortb* wot   = (ushortb*)(wb + 2097152);              // [512][512]
    ushortb* l1wt  = (ushortb*)(wb + 2621440);              // [2048][512]
    ushortb* l2wt  = (ushortb*)(wb + 4718592);              // [512][2048]
    float*   pe    = (float*)  (wb + 6815744);              // [1024][512] fp32
    float*   zbuf  = (float*)  (wb + 8912896);              // [16][2] + counter
    unsigned* done = (unsigned*)(zbuf + 32);

    const int M = 16384;
    const float qscale = 0.12753139626997592f;  // log2(e)/sqrt(128)

    // prep: one merged dispatch (includes zbuf/done zeroing)
    prep_all<<<11072, 256, 0, stream>>>(
        x, xb, pe, emb_w, WO, embwt, wot,
        WQ, WK, WV, wqkvt, qscale, l1w, l1wt, l2w, l2wt,
        (unsigned*)zbuf);

    // 1) h0 = x @ emb_w + emb_b + pe
    gemm_mfma<EP_EMB><<<dim3(M / 128, 4), 256, 0, stream>>>(
        xb, embwt, emb_b, nullptr, pe, h0b, M, 512, 512);

    // 2) fused QKV projection (Q scale baked; V transposed in epilogue)
    gemm_mfma<EP_QKV><<<dim3(M / 128, 12), 256, 0, stream>>>(
        h0b, wqkvt, nullptr, nullptr, nullptr, Qb, M, 1536, 512);

    // 3) flash attention -> headR bf16 ([B,H,S,DK] flat == raw reshape)
    attn_mfma<<<512, 256, 0, stream>>>(Qb, Kb, Vt, headR);

    // 4) r1 = headR @ WO + h0 ; ln1 = LN(r1)
    gemm_mfma<EP_RES><<<dim3(M / 128, 4), 256, 0, stream>>>(
        headR, wot, nullptr, h0b, nullptr, r1, M, 512, 512);
    ln_kernel<<<M / 4, 256, 0, stream>>>(r1, g1, b1, ln1);

    // 5) FFN: 256^2-BK64 up-proj (grid 64x8 = 512 blocks), 128^2 down-proj
    gemm_256<<<dim3(M / 256, 8), 512, 0, stream>>>(
        ln1, l1wt, l1b, mid, M, 2048, 512);
    gemm_mfma<EP_BIAS_RES><<<dim3(M / 128, 4), 256, 0, stream>>>(
        mid, l2wt, l2b, ln1, nullptr, r2, M, 512, 2048);
    ln_kernel<<<M / 4, 256, 0, stream>>>(r2, g2, b2, ln2);

    // 6) maxpool + FC + log_softmax (single fused dispatch, last-block logits)
    final_fused<<<dim3(16, 16), 256, 0, stream>>>(ln2, fcw, fcb, zbuf, done, out);
}

// Round 8
// 339.394 us; speedup vs baseline: 1.0196x; 1.0196x over previous
//
#include <hip/hip_runtime.h>

typedef unsigned short ushortb;
typedef __attribute__((ext_vector_type(8))) short short8;    // 8 bf16 = 16B (MFMA A/B frag)
typedef __attribute__((ext_vector_type(4))) float f32x4;     // MFMA C/D frag

__device__ __forceinline__ ushortb f2bb(float f) {
    union { float f; unsigned u; } x; x.f = f;
    unsigned r = x.u + 0x7fffu + ((x.u >> 16) & 1u);   // RNE
    return (ushortb)(r >> 16);
}
__device__ __forceinline__ float bb2f(ushortb u) {
    union { unsigned u; float f; } x; x.u = ((unsigned)u) << 16; return x.f;
}

// packed fp32x2 -> bf16x2 (low|high), RNE. gfx950 v_cvt_pk_bf16_f32 if available.
__device__ __forceinline__ unsigned pkbb(float a, float b) {
#if __has_builtin(__builtin_amdgcn_cvt_pk_bf16_f32)
    auto p = __builtin_amdgcn_cvt_pk_bf16_f32(a, b);
    unsigned u; __builtin_memcpy(&u, &p, 4);
    return u;
#else
    return (unsigned)f2bb(a) | ((unsigned)f2bb(b) << 16);
#endif
}

#if __has_builtin(__builtin_amdgcn_exp2f)
#define EXP2(x) __builtin_amdgcn_exp2f(x)
#else
#define EXP2(x) exp2f(x)
#endif

// async global->LDS DMA, 16B/lane; lds base wave-uniform, lane -> base+lane*16
__device__ __forceinline__ void async_ld16(void* lds, const void* g) {
    __builtin_amdgcn_global_load_lds(
        (const __attribute__((address_space(1))) void*)g,
        (__attribute__((address_space(3))) void*)lds, 16, 0, 0);
}

// ---------------------------------------------------------------------------
#define EP_EMB       0   // + bias + pe table
#define EP_RES       2   // + bf16 residual
#define EP_BIAS_RELU 3   // + bias, relu
#define EP_BIAS_RES  4   // + bias + bf16 residual
#define EP_QKV       7   // N=1536 fused: cols<1024 -> Qb/Kb, cols>=1024 -> Vt transposed

// C[M,N] = A[M,K] @ Bt[N,K]^T (+ epilogue). bf16 in, fp32 MFMA accum, bf16 out.
// Block 256 thr (4 waves 2x2), tile 128x128, BK=64, double-buffered
// global_load_lds staging; XOR-swizzled unpadded LDS. 64 KB LDS -> 2 blk/CU
// (cross-block overlap hides the per-tile barrier drain -- m114).
template <int EP>
__global__ __launch_bounds__(256) void gemm_mfma(
    const ushortb* __restrict__ A, const ushortb* __restrict__ Bt,
    const float* __restrict__ bias, const ushortb* __restrict__ res,
    const float* __restrict__ pe, ushortb* __restrict__ C,
    int M, int N, int K)
{
    __shared__ ushortb sA[2][128][64];   // 32 KB
    __shared__ ushortb sB[2][128][64];   // 32 KB

    const int tid = threadIdx.x;
    const int wave = tid >> 6, lane = tid & 63;
    const int quad = lane >> 4, l15 = lane & 15;
    const int row0 = blockIdx.x * 128;
    const int col0 = blockIdx.y * 128;
    const int wm = (wave >> 1) * 64, wn = (wave & 1) * 64;
    const int srl = lane >> 3, slot = lane & 7;

    f32x4 acc[4][4];
    #pragma unroll
    for (int i = 0; i < 4; ++i)
        #pragma unroll
        for (int j = 0; j < 4; ++j) acc[i][j] = (f32x4){0.f, 0.f, 0.f, 0.f};

    // initial stage -> buffer 0
    #pragma unroll
    for (int c = 0; c < 4; ++c) {
        int rbase = wave * 32 + c * 8;
        int r = rbase + srl;
        int ka = (slot ^ ((r ^ (r >> 3)) & 7)) * 8;
        async_ld16(&sA[0][rbase][0], A  + (size_t)(row0 + r) * K + ka);
        async_ld16(&sB[0][rbase][0], Bt + (size_t)(col0 + r) * K + ka);
    }

    int buf = 0;
    for (int k0 = 0; k0 < K; k0 += 64) {
        __syncthreads();   // drains DMA for 'buf' + prev compute
        if (k0 + 64 < K) {
            int nb = buf ^ 1;
            #pragma unroll
            for (int c = 0; c < 4; ++c) {
                int rbase = wave * 32 + c * 8;
                int r = rbase + srl;
                int ka = (slot ^ ((r ^ (r >> 3)) & 7)) * 8;
                async_ld16(&sA[nb][rbase][0], A  + (size_t)(row0 + r) * K + k0 + 64 + ka);
                async_ld16(&sB[nb][rbase][0], Bt + (size_t)(col0 + r) * K + k0 + 64 + ka);
            }
        }
        #pragma unroll
        for (int kc = 0; kc < 2; ++kc) {
            short8 af[4], bf[4];
            #pragma unroll
            for (int i = 0; i < 4; ++i) {
                int m = wm + i * 16 + l15;
                af[i] = *(const short8*)&sA[buf][m][(((kc * 4 + quad) ^ ((m ^ (m >> 3)) & 7))) * 8];
            }
            #pragma unroll
            for (int j = 0; j < 4; ++j) {
                int n = wn + j * 16 + l15;
                bf[j] = *(const short8*)&sB[buf][n][(((kc * 4 + quad) ^ ((n ^ (n >> 3)) & 7))) * 8];
            }
            #pragma unroll
            for (int i = 0; i < 4; ++i)
                #pragma unroll
                for (int j = 0; j < 4; ++j)
                    acc[i][j] = __builtin_amdgcn_mfma_f32_16x16x32_bf16(af[i], bf[j], acc[i][j], 0, 0, 0);
        }
        buf ^= 1;
    }

    if constexpr (EP == EP_QKV) {
        if (col0 < 1024) {
            ushortb* dst = C + ((size_t)(col0 >> 9)) * ((size_t)M * 512);
            #pragma unroll
            for (int i = 0; i < 4; ++i)
                #pragma unroll
                for (int r = 0; r < 4; ++r) {
                    int row = row0 + wm + i * 16 + quad * 4 + r;
                    #pragma unroll
                    for (int j = 0; j < 4; ++j) {
                        int col = (col0 + wn + j * 16 + l15) & 511;
                        dst[(size_t)row * 512 + col] = f2bb(acc[i][j][r]);
                    }
                }
        } else {
            ushortb* Vt = C + (size_t)2 * M * 512;
            int bb_ = row0 >> 10;
            #pragma unroll
            for (int i = 0; i < 4; ++i) {
                int s = (row0 & 1023) + wm + i * 16 + quad * 4;
                #pragma unroll
                for (int j = 0; j < 4; ++j) {
                    int vcol = col0 + wn + j * 16 + l15 - 1024;
                    int h = vcol >> 7, e = vcol & 127;
                    uint2 v;
                    v.x = pkbb(acc[i][j][0], acc[i][j][1]);
                    v.y = pkbb(acc[i][j][2], acc[i][j][3]);
                    *(uint2*)&Vt[((size_t)((bb_ * 4 + h) * 128 + e) << 10) + s] = v;
                }
            }
        }
        return;
    }

    #pragma unroll
    for (int i = 0; i < 4; ++i) {
        #pragma unroll
        for (int r = 0; r < 4; ++r) {
            int row = row0 + wm + i * 16 + quad * 4 + r;
            #pragma unroll
            for (int j = 0; j < 4; ++j) {
                int col = col0 + wn + j * 16 + l15;
                float v = acc[i][j][r];
                if constexpr (EP == EP_EMB) {
                    v += bias[col] + pe[((row & 1023) << 9) + col];
                } else if constexpr (EP == EP_RES) {
                    v += bb2f(res[(size_t)row * N + col]);
                } else if constexpr (EP == EP_BIAS_RELU) {
                    v = fmaxf(v + bias[col], 0.0f);
                } else if constexpr (EP == EP_BIAS_RES) {
                    v += bias[col] + bb2f(res[(size_t)row * N + col]);
                }
                C[(size_t)row * N + col] = f2bb(v);
            }
        }
    }
}

// ---------------------------------------------------------------------------
// 256x256-tile GEMM, BK=64, 2-phase __syncthreads structure, 128 KB LDS
// (1 blk/CU; 256^2 wave tile needs >128 VGPR so 2 blk/CU is infeasible --
// round-5 spill disaster). 512 thr (8 waves, 2M x 4N), wave tile 128x64.
// 0.375 ds_read/MFMA vs 0.5 on the 128^2 tile. Bias+ReLU epilogue (FFN1).
__global__ __launch_bounds__(512, 2) void gemm_256(
    const ushortb* __restrict__ A, const ushortb* __restrict__ Bt,
    const float* __restrict__ bias, ushortb* __restrict__ C,
    int M, int N, int K)
{
    __shared__ ushortb sA[2][256][64];   // 64 KB
    __shared__ ushortb sB[2][256][64];   // 64 KB

    const int tid = threadIdx.x;
    const int wave = tid >> 6, lane = tid & 63;
    const int quad = lane >> 4, l15 = lane & 15;
    const int row0 = blockIdx.x * 256;
    const int col0 = blockIdx.y * 256;
    const int wm = (wave >> 2) * 128;    // 2 row groups of 128
    const int wn = (wave & 3) * 64;      // 4 col groups of 64
    const int srl = lane >> 3, slot = lane & 7;

    f32x4 acc[8][4];
    #pragma unroll
    for (int i = 0; i < 8; ++i)
        #pragma unroll
        for (int j = 0; j < 4; ++j) acc[i][j] = (f32x4){0.f, 0.f, 0.f, 0.f};

    // initial stage -> buffer 0 (per wave: rows wave*32..wave*32+31 of A and B)
    #pragma unroll
    for (int c = 0; c < 4; ++c) {
        int rbase = wave * 32 + c * 8;
        int r = rbase + srl;
        int ka = (slot ^ ((r ^ (r >> 3)) & 7)) * 8;
        async_ld16(&sA[0][rbase][0], A  + (size_t)(row0 + r) * K + ka);
        async_ld16(&sB[0][rbase][0], Bt + (size_t)(col0 + r) * K + ka);
    }

    int buf = 0;
    for (int k0 = 0; k0 < K; k0 += 64) {
        __syncthreads();   // drains DMA for 'buf' + prev compute
        if (k0 + 64 < K) {
            int nb = buf ^ 1;
            #pragma unroll
            for (int c = 0; c < 4; ++c) {
                int rbase = wave * 32 + c * 8;
                int r = rbase + srl;
                int ka = (slot ^ ((r ^ (r >> 3)) & 7)) * 8;
                async_ld16(&sA[nb][rbase][0], A  + (size_t)(row0 + r) * K + k0 + 64 + ka);
                async_ld16(&sB[nb][rbase][0], Bt + (size_t)(col0 + r) * K + k0 + 64 + ka);
            }
        }
        #pragma unroll
        for (int kc = 0; kc < 2; ++kc) {
            short8 af[8], bf[4];
            #pragma unroll
            for (int i = 0; i < 8; ++i) {
                int m = wm + i * 16 + l15;
                af[i] = *(const short8*)&sA[buf][m][(((kc * 4 + quad) ^ ((m ^ (m >> 3)) & 7))) * 8];
            }
            #pragma unroll
            for (int j = 0; j < 4; ++j) {
                int n = wn + j * 16 + l15;
                bf[j] = *(const short8*)&sB[buf][n][(((kc * 4 + quad) ^ ((n ^ (n >> 3)) & 7))) * 8];
            }
            #pragma unroll
            for (int i = 0; i < 8; ++i)
                #pragma unroll
                for (int j = 0; j < 4; ++j)
                    acc[i][j] = __builtin_amdgcn_mfma_f32_16x16x32_bf16(af[i], bf[j], acc[i][j], 0, 0, 0);
        }
        buf ^= 1;
    }

    #pragma unroll
    for (int i = 0; i < 8; ++i) {
        #pragma unroll
        for (int r = 0; r < 4; ++r) {
            int row = row0 + wm + i * 16 + quad * 4 + r;
            #pragma unroll
            for (int j = 0; j < 4; ++j) {
                int col = col0 + wn + j * 16 + l15;
                float v = fmaxf(acc[i][j][r] + bias[col], 0.0f);
                C[(size_t)row * N + col] = f2bb(v);
            }
        }
    }
}

// ---------------------------------------------------------------------------
// Merged prep kernel: all six independent prep stages in one dispatch over a
// partitioned 1D grid (block-uniform branch). Saves launch gaps + tails.
// Block 8192 additionally zeros the zbuf accumulators + done-counter (33 u32).
//   [0,8192)        conv_x: x fp32 -> xb bf16 (4 elems/thread)
//   [8192,10240)    pe table fp32 [1024][512]
//   [10240,10368)   pairT512: emb_w (z=0) / WO (z=1) transpose, 8x8x2
//   [10368,10560)   qkvT: WQ/WK/WV [512][128] -> wqkvt rows, 2x8x12, Q scaled
//   [10560,10816)   tileT l1w [512][2048] -> l1wt, 32x8
//   [10816,11072)   tileT l2w [2048][512] -> l2wt, 8x32
__global__ __launch_bounds__(256) void prep_all(
    const float* __restrict__ x, ushortb* __restrict__ xb,
    float* __restrict__ pe,
    const float* __restrict__ emb_w, const float* __restrict__ WO,
    ushortb* __restrict__ embwt, ushortb* __restrict__ wot,
    const float* __restrict__ WQ, const float* __restrict__ WK,
    const float* __restrict__ WV, ushortb* __restrict__ wqkvt, float qscale,
    const float* __restrict__ l1w, ushortb* __restrict__ l1wt,
    const float* __restrict__ l2w, ushortb* __restrict__ l2wt,
    unsigned* __restrict__ zinit)
{
    __shared__ float t[64][65];
    const int bid = blockIdx.x;
    const int tid = threadIdx.x;

    if (bid < 8192) {                       // conv_x
        size_t i4 = (size_t)bid * 256 + tid;
        float4 v = *(const float4*)(x + i4 * 4);
        ushort4 o;
        o.x = f2bb(v.x); o.y = f2bb(v.y); o.z = f2bb(v.z); o.w = f2bb(v.w);
        *(ushort4*)(xb + i4 * 4) = o;
        return;
    }
    if (bid < 10240) {                      // pe table (+ zbuf/counter zero)
        if (bid == 8192 && tid < 33) zinit[tid] = 0u;
        int idx = (bid - 8192) * 256 + tid;  // s*512 + c
        int s = idx >> 9, c = idx & 511;
        float div = expf((float)(c & ~1) * (-9.210340371976184f / 512.0f));
        float ang = (float)s * div;
        pe[idx] = (c & 1) ? cosf(ang) : sinf(ang);
        return;
    }

    const int tx = tid & 63, ty = tid >> 6;

    if (bid < 10368) {                      // pairT512 (8x8x2)
        int b2 = bid - 10240;
        int c0 = (b2 & 7) * 64, r0 = ((b2 >> 3) & 7) * 64, z = b2 >> 6;
        const float* in = z ? WO : emb_w;
        ushortb* out = z ? wot : embwt;
        #pragma unroll
        for (int i = 0; i < 16; ++i) {
            int r = ty + i * 4;
            t[r][tx] = in[(size_t)(r0 + r) * 512 + c0 + tx];
        }
        __syncthreads();
        #pragma unroll
        for (int i = 0; i < 16; ++i) {
            int r = ty + i * 4;
            out[(size_t)(c0 + r) * 512 + r0 + tx] = f2bb(t[tx][r]);
        }
        return;
    }
    if (bid < 10560) {                      // qkvT (2x8x12)
        int b3 = bid - 10368;
        int c0 = (b3 & 1) * 64, r0 = ((b3 >> 1) & 7) * 64, z = b3 >> 4;
        int sel = z >> 2, zz = z & 3;
        const float* in = (sel == 0 ? WQ : (sel == 1 ? WK : WV)) + (size_t)zz * 65536;
        ushortb* out = wqkvt + (size_t)sel * 262144 + (size_t)zz * 65536;
        const float scale = (sel == 0) ? qscale : 1.0f;
        #pragma unroll
        for (int i = 0; i < 16; ++i) {
            int r = ty + i * 4;
            t[r][tx] = in[(size_t)(r0 + r) * 128 + c0 + tx] * scale;
        }
        __syncthreads();
        #pragma unroll
        for (int i = 0; i < 16; ++i) {
            int r = ty + i * 4;
            out[(size_t)(c0 + r) * 512 + r0 + tx] = f2bb(t[tx][r]);
        }
        return;
    }
    if (bid < 10816) {                      // tileT l1w: [512][2048] -> [2048][512]
        int b4 = bid - 10560;
        int c0 = (b4 & 31) * 64, r0 = (b4 >> 5) * 64;
        #pragma unroll
        for (int i = 0; i < 16; ++i) {
            int r = ty + i * 4;
            t[r][tx] = l1w[(size_t)(r0 + r) * 2048 + c0 + tx];
        }
        __syncthreads();
        #pragma unroll
        for (int i = 0; i < 16; ++i) {
            int r = ty + i * 4;
            l1wt[(size_t)(c0 + r) * 512 + r0 + tx] = f2bb(t[tx][r]);
        }
        return;
    }
    {                                       // tileT l2w: [2048][512] -> [512][2048]
        int b5 = bid - 10816;
        int c0 = (b5 & 7) * 64, r0 = (b5 >> 3) * 64;
        #pragma unroll
        for (int i = 0; i < 16; ++i) {
            int r = ty + i * 4;
            t[r][tx] = l2w[(size_t)(r0 + r) * 512 + c0 + tx];
        }
        __syncthreads();
        #pragma unroll
        for (int i = 0; i < 16; ++i) {
            int r = ty + i * 4;
            l2wt[(size_t)(c0 + r) * 2048 + r0 + tx] = f2bb(t[tx][r]);
        }
        return;
    }
}

// ---------------------------------------------------------------------------
// MFMA flash attention, fixed-max softmax, double-buffered DMA K/V staging,
// XCD-local grid, packed bf16 conversions. Q pre-scaled by log2(e)/sqrt(128).
// Round-0 structure (__syncthreads double-buffer) with PAIRED staging:
// each sync period stages TWO 32-wide K/V tiles (sub-buffers, inner layouts
// unchanged) and runs the tile body twice -> 16 barrier drains instead of 32.
// NO setprio: the 4 waves are lockstep-barrier-synced (m190 regime, where
// setprio measured negative) -- round-7/round-8 A/B.
__global__ __launch_bounds__(256) void attn_mfma(
    const ushortb* __restrict__ Qb, const ushortb* __restrict__ Kb,
    const ushortb* __restrict__ Vt, ushortb* __restrict__ O)
{
    __shared__ ushortb sK[2][2][32][128];    // 32 KB
    __shared__ ushortb sVt[2][2][128][32];   // 32 KB
    __shared__ ushortb sP[4][32][40];        // 10 KB, [wave][q_local][t]

    const int tid = threadIdx.x;
    const int wave = tid >> 6, lane = tid & 63;
    const int quad = lane >> 4, l15 = lane & 15;
    const int bid = blockIdx.x;          // XCD swizzle: same (b,h) -> ids 64 apart
    const int bh = bid & 63, qc = bid >> 6;
    const int b = bh >> 2, h = bh & 3;
    const int q0 = qc * 128 + wave * 32;
    const size_t qk_off = ((size_t)b << 10) * 512 + h * 128;
    const ushortb* Qp = Qb + qk_off;
    const ushortb* Kp = Kb + qk_off;
    const ushortb* Vp = Vt + (((size_t)(b * 4 + h)) << 17);

    short8 qfA[4], qfB[4];   // B-frags: Q[q=l15 | 16+l15][k=quad*8+j]
    {
        const ushortb* qa = Qp + (size_t)(q0 + l15) * 512;
        const ushortb* qb = Qp + (size_t)(q0 + 16 + l15) * 512;
        #pragma unroll
        for (int kc = 0; kc < 4; ++kc) {
            qfA[kc] = *(const short8*)(qa + kc * 32 + quad * 8);
            qfB[kc] = *(const short8*)(qb + kc * 32 + quad * 8);
        }
    }

    f32x4 oA[8], oB[8];
    #pragma unroll
    for (int dt = 0; dt < 8; ++dt) {
        oA[dt] = (f32x4){0.f, 0.f, 0.f, 0.f};
        oB[dt] = (f32x4){0.f, 0.f, 0.f, 0.f};
    }
    float lA = 0.f, lB = 0.f;

    // initial stage: pair of tiles (t=0,32) -> buffer 0
    #pragma unroll
    for (int s = 0; s < 2; ++s) {
        #pragma unroll
        for (int c = 0; c < 2; ++c) {
            int seg = wave * 2 + c;
            int rk = seg * 4 + (lane >> 4);
            int ck = (lane & 15) ^ (rk & 15);
            async_ld16(&sK[0][s][seg * 4][0], Kp + (size_t)(s * 32 + rk) * 512 + ck * 8);
            int dv = seg * 16 + (lane >> 2);
            int cv = (lane & 3) ^ (dv & 3);
            async_ld16(&sVt[0][s][seg * 16][0], Vp + ((size_t)dv << 10) + s * 32 + cv * 8);
        }
    }

    int buf = 0;
    for (int t0 = 0; t0 < 1024; t0 += 64) {
        __syncthreads();   // DMA for 'buf' (both subs) complete + prev compute done
        if (t0 + 64 < 1024) {
            int nb = buf ^ 1;
            #pragma unroll
            for (int s = 0; s < 2; ++s) {
                #pragma unroll
                for (int c = 0; c < 2; ++c) {
                    int seg = wave * 2 + c;
                    int rk = seg * 4 + (lane >> 4);
                    int ck = (lane & 15) ^ (rk & 15);
                    async_ld16(&sK[nb][s][seg * 4][0],
                               Kp + (size_t)(t0 + 64 + s * 32 + rk) * 512 + ck * 8);
                    int dv = seg * 16 + (lane >> 2);
                    int cv = (lane & 3) ^ (dv & 3);
                    async_ld16(&sVt[nb][s][seg * 16][0],
                               Vp + ((size_t)dv << 10) + t0 + 64 + s * 32 + cv * 8);
                }
            }
        }

        #pragma unroll
        for (int sub = 0; sub < 2; ++sub) {
            // S^T: D[t][q]; t = quad*4+reg (+0/16), q = l15 (A-group) / 16+l15 (B)
            f32x4 sA0 = {0,0,0,0}, sA1 = {0,0,0,0}, sB0 = {0,0,0,0}, sB1 = {0,0,0,0};
            #pragma unroll
            for (int kc = 0; kc < 4; ++kc) {
                short8 k0f = *(const short8*)&sK[buf][sub][l15][((kc * 4 + quad) ^ l15) * 8];
                short8 k1f = *(const short8*)&sK[buf][sub][16 + l15][((kc * 4 + quad) ^ l15) * 8];
                sA0 = __builtin_amdgcn_mfma_f32_16x16x32_bf16(k0f, qfA[kc], sA0, 0, 0, 0);
                sA1 = __builtin_amdgcn_mfma_f32_16x16x32_bf16(k1f, qfA[kc], sA1, 0, 0, 0);
                sB0 = __builtin_amdgcn_mfma_f32_16x16x32_bf16(k0f, qfB[kc], sB0, 0, 0, 0);
                sB1 = __builtin_amdgcn_mfma_f32_16x16x32_bf16(k1f, qfB[kc], sB1, 0, 0, 0);
            }

            // fixed-max softmax: p = 2^score (log2e baked into Q scale)
            float pA0[4], pA1[4], pB0[4], pB1[4];
            float sumA = 0.f, sumB = 0.f;
            #pragma unroll
            for (int r = 0; r < 4; ++r) {
                pA0[r] = EXP2(sA0[r]); pA1[r] = EXP2(sA1[r]);
                pB0[r] = EXP2(sB0[r]); pB1[r] = EXP2(sB1[r]);
                sumA += pA0[r] + pA1[r];
                sumB += pB0[r] + pB1[r];
            }
            lA += sumA; lB += sumB;

            // store P[q][t] bf16 via packed converts (2 x uint2 per q-row half)
            uint2 w;
            w.x = pkbb(pA0[0], pA0[1]); w.y = pkbb(pA0[2], pA0[3]);
            *(uint2*)&sP[wave][l15][quad * 4] = w;
            w.x = pkbb(pA1[0], pA1[1]); w.y = pkbb(pA1[2], pA1[3]);
            *(uint2*)&sP[wave][l15][16 + quad * 4] = w;
            w.x = pkbb(pB0[0], pB0[1]); w.y = pkbb(pB0[2], pB0[3]);
            *(uint2*)&sP[wave][16 + l15][quad * 4] = w;
            w.x = pkbb(pB1[0], pB1[1]); w.y = pkbb(pB1[2], pB1[3]);
            *(uint2*)&sP[wave][16 + l15][16 + quad * 4] = w;

            short8 pfA = *(const short8*)&sP[wave][l15][quad * 8];
            short8 pfB = *(const short8*)&sP[wave][16 + l15][quad * 8];

            #pragma unroll
            for (int dt = 0; dt < 8; ++dt) {
                int d = dt * 16 + l15;
                short8 vfrag = *(const short8*)&sVt[buf][sub][d][(quad ^ (d & 3)) * 8];
                oA[dt] = __builtin_amdgcn_mfma_f32_16x16x32_bf16(pfA, vfrag, oA[dt], 0, 0, 0);
                oB[dt] = __builtin_amdgcn_mfma_f32_16x16x32_bf16(pfB, vfrag, oB[dt], 0, 0, 0);
            }
        }
        buf ^= 1;
    }

    lA += __shfl_xor(lA, 16); lA += __shfl_xor(lA, 32);
    lB += __shfl_xor(lB, 16); lB += __shfl_xor(lB, 32);

    const size_t obase = (((size_t)(b * 4 + h) << 10) + q0) << 7;
    #pragma unroll
    for (int r = 0; r < 4; ++r) {
        float invA = 1.0f / __shfl(lA, quad * 4 + r);
        float invB = 1.0f / __shfl(lB, quad * 4 + r);
        int qa = quad * 4 + r, qb = 16 + quad * 4 + r;
        #pragma unroll
        for (int dt = 0; dt < 8; ++dt) {
            O[obase + ((size_t)qa << 7) + dt * 16 + l15] = f2bb(oA[dt][r] * invA);
            O[obase + ((size_t)qb << 7) + dt * 16 + l15] = f2bb(oB[dt][r] * invB);
        }
    }
}

// ---------------------------------------------------------------------------
// LayerNorm over 512 features: wave per row, 8 elems/lane, shuffle reduce.
__global__ __launch_bounds__(256) void ln_kernel(const ushortb* __restrict__ in,
                                                 const float* __restrict__ g,
                                                 const float* __restrict__ bta,
                                                 ushortb* __restrict__ out)
{
    const int lane = threadIdx.x & 63, w = threadIdx.x >> 6;
    const size_t row = (size_t)blockIdx.x * 4 + w;
    const int e0 = lane * 8;
    short8 v8 = *(const short8*)(in + row * 512 + e0);
    float v[8];
    #pragma unroll
    for (int k = 0; k < 8; ++k) v[k] = bb2f((ushortb)((short*)&v8)[k]);
    float s = 0.f, sq = 0.f;
    #pragma unroll
    for (int k = 0; k < 8; ++k) { s += v[k]; sq += v[k] * v[k]; }
    #pragma unroll
    for (int o = 1; o < 64; o <<= 1) { s += __shfl_xor(s, o); sq += __shfl_xor(sq, o); }
    float mu = s * (1.0f / 512.0f);
    float var = sq * (1.0f / 512.0f) - mu * mu;
    float rstd = rsqrtf(var + 1e-5f);
    float4 g0 = *(const float4*)(g + e0),  g1 = *(const float4*)(g + e0 + 4);
    float4 b0 = *(const float4*)(bta + e0), b1 = *(const float4*)(bta + e0 + 4);
    float gg[8] = {g0.x, g0.y, g0.z, g0.w, g1.x, g1.y, g1.z, g1.w};
    float bb[8] = {b0.x, b0.y, b0.z, b0.w, b1.x, b1.y, b1.z, b1.w};
    short8 o8;
    #pragma unroll
    for (int k = 0; k < 8; ++k)
        ((short*)&o8)[k] = (short)f2bb((v[k] - mu) * rstd * gg[k] + bb[k]);
    *(short8*)(out + row * 512 + e0) = o8;
}

// ---------------------------------------------------------------------------
// MaxPool1d(16) + FC[32768,2] + log_softmax fused: grid (16 batch, 16 chunks),
// atomicAdd partials into zbuf; last block (device-scope ticket) computes the
// logits. done counter sits at zbuf+32 (both zeroed by prep_all each run).
__global__ __launch_bounds__(256) void final_fused(const ushortb* __restrict__ ln2,
                                                   const float* __restrict__ fcw,
                                                   const float* __restrict__ fcb,
                                                   float* __restrict__ zbuf,
                                                   unsigned* __restrict__ done,
                                                   float* __restrict__ out)
{
    const int b = blockIdx.x, chunk = blockIdx.y;
    const int tid = threadIdx.x;
    float a0 = 0.0f, a1 = 0.0f;
    #pragma unroll
    for (int t = 0; t < 8; ++t) {
        int m = chunk * 2048 + t * 256 + tid;
        int s = m >> 5, j = m & 31;
        const ushortb* p = ln2 + (((size_t)(b * 1024 + s)) << 9) + j * 16;
        float mx = -1e30f;
        #pragma unroll
        for (int e = 0; e < 16; ++e) mx = fmaxf(mx, bb2f(p[e]));
        a0 += mx * fcw[2 * m];
        a1 += mx * fcw[2 * m + 1];
    }
    __shared__ float r0[256], r1[256];
    __shared__ unsigned lastf;
    r0[tid] = a0; r1[tid] = a1;
    __syncthreads();
    for (int o = 128; o > 0; o >>= 1) {
        if (tid < o) { r0[tid] += r0[tid + o]; r1[tid] += r1[tid + o]; }
        __syncthreads();
    }
    if (tid == 0) {
        atomicAdd(&zbuf[2 * b],     r0[0]);
        atomicAdd(&zbuf[2 * b + 1], r1[0]);
        __threadfence();                       // order partials before ticket
        lastf = (atomicAdd(done, 1u) == 255u); // 256 blocks total
    }
    __syncthreads();
    if (lastf && tid < 16) {
        __threadfence();
        // coherent reads of all partials via device-scope atomic no-ops
        float z0 = atomicAdd(&zbuf[2 * tid], 0.0f)     + fcb[0];
        float z1 = atomicAdd(&zbuf[2 * tid + 1], 0.0f) + fcb[1];
        float mx = fmaxf(z0, z1);
        float lse = mx + logf(expf(z0 - mx) + expf(z1 - mx));
        out[2 * tid]     = z0 - lse;
        out[2 * tid + 1] = z1 - lse;
    }
}

// ---------------------------------------------------------------------------
extern "C" void kernel_launch(void* const* d_in, const int* in_sizes, int n_in,
                              void* d_out, int out_size, void* d_ws, size_t ws_size,
                              hipStream_t stream)
{
    const float* x     = (const float*)d_in[0];
    const float* emb_w = (const float*)d_in[1];
    const float* emb_b = (const float*)d_in[2];
    const float* WQ    = (const float*)d_in[3];
    const float* WK    = (const float*)d_in[4];
    const float* WV    = (const float*)d_in[5];
    const float* WO    = (const float*)d_in[6];
    const float* g1    = (const float*)d_in[7];
    const float* b1    = (const float*)d_in[8];
    const float* l1w   = (const float*)d_in[9];
    const float* l1b   = (const float*)d_in[10];
    const float* l2w   = (const float*)d_in[11];
    const float* l2b   = (const float*)d_in[12];
    const float* g2    = (const float*)d_in[13];
    const float* b2    = (const float*)d_in[14];
    const float* fcw   = (const float*)d_in[15];
    const float* fcb   = (const float*)d_in[16];
    float* out = (float*)d_out;

    char* ws = (char*)d_ws;
    const size_t Ub = (size_t)16384 * 512 * 2;   // 16.78 MB bf16 activation unit
    // u0: xb -> r1 -> r2   u1: h0b -> ln2   u2: Qb -> ln1
    // u3: Kb -> mid[0]     u4: Vt -> mid[1] u5: headR -> mid[2]  u6: mid[3]
    ushortb* xb    = (ushortb*)(ws + 0 * Ub);
    ushortb* h0b   = (ushortb*)(ws + 1 * Ub);
    ushortb* Qb    = (ushortb*)(ws + 2 * Ub);   // Kb = Qb + M*512, Vt = Qb + 2*M*512
    ushortb* Kb    = (ushortb*)(ws + 3 * Ub);
    ushortb* Vt    = (ushortb*)(ws + 4 * Ub);
    ushortb* headR = (ushortb*)(ws + 5 * Ub);
    ushortb* mid   = (ushortb*)(ws + 3 * Ub);   // [16384,2048] over u3..u6
    ushortb* r1    = xb;
    ushortb* ln1   = Qb;
    ushortb* r2    = xb;
    ushortb* ln2   = h0b;
    char* wb = ws + 7 * Ub;
    ushortb* embwt = (ushortb*)(wb);                        // [512][512]
    ushortb* wqkvt = (ushortb*)(wb + 524288);               // [1536][512]
    ushortb* wot   = (ushortb*)(wb + 2097152);              // [512][512]
    ushortb* l1wt  = (ushortb*)(wb + 2621440);              // [2048][512]
    ushortb* l2wt  = (ushortb*)(wb + 4718592);              // [512][2048]
    float*   pe    = (float*)  (wb + 6815744);              // [1024][512] fp32
    float*   zbuf  = (float*)  (wb + 8912896);              // [16][2] + counter
    unsigned* done = (unsigned*)(zbuf + 32);

    const int M = 16384;
    const float qscale = 0.12753139626997592f;  // log2(e)/sqrt(128)

    // prep: one merged dispatch (includes zbuf/done zeroing)
    prep_all<<<11072, 256, 0, stream>>>(
        x, xb, pe, emb_w, WO, embwt, wot,
        WQ, WK, WV, wqkvt, qscale, l1w, l1wt, l2w, l2wt,
        (unsigned*)zbuf);

    // 1) h0 = x @ emb_w + emb_b + pe
    gemm_mfma<EP_EMB><<<dim3(M / 128, 4), 256, 0, stream>>>(
        xb, embwt, emb_b, nullptr, pe, h0b, M, 512, 512);

    // 2) fused QKV projection (Q scale baked; V transposed in epilogue)
    gemm_mfma<EP_QKV><<<dim3(M / 128, 12), 256, 0, stream>>>(
        h0b, wqkvt, nullptr, nullptr, nullptr, Qb, M, 1536, 512);

    // 3) flash attention -> headR bf16 ([B,H,S,DK] flat == raw reshape)
    attn_mfma<<<512, 256, 0, stream>>>(Qb, Kb, Vt, headR);

    // 4) r1 = headR @ WO + h0 ; ln1 = LN(r1)
    gemm_mfma<EP_RES><<<dim3(M / 128, 4), 256, 0, stream>>>(
        headR, wot, nullptr, h0b, nullptr, r1, M, 512, 512);
    ln_kernel<<<M / 4, 256, 0, stream>>>(r1, g1, b1, ln1);

    // 5) FFN: 256^2-BK64 up-proj (grid 64x8 = 512 blocks), 128^2 down-proj
    gemm_256<<<dim3(M / 256, 8), 512, 0, stream>>>(
        ln1, l1wt, l1b, mid, M, 2048, 512);
    gemm_mfma<EP_BIAS_RES><<<dim3(M / 128, 4), 256, 0, stream>>>(
        mid, l2wt, l2b, ln1, nullptr, r2, M, 512, 2048);
    ln_kernel<<<M / 4, 256, 0, stream>>>(r2, g2, b2, ln2);

    // 6) maxpool + FC + log_softmax (single fused dispatch, last-block logits)
    final_fused<<<dim3(16, 16), 256, 0, stream>>>(ln2, fcw, fcb, zbuf, done, out);
}

// Round 9
// 337.888 us; speedup vs baseline: 1.0241x; 1.0045x over previous
//
#include <hip/hip_runtime.h>

typedef unsigned short ushortb;
typedef __attribute__((ext_vector_type(8))) short short8;    // 8 bf16 = 16B (MFMA A/B frag)
typedef __attribute__((ext_vector_type(4))) float f32x4;     // MFMA C/D frag

__device__ __forceinline__ ushortb f2bb(float f) {
    union { float f; unsigned u; } x; x.f = f;
    unsigned r = x.u + 0x7fffu + ((x.u >> 16) & 1u);   // RNE
    return (ushortb)(r >> 16);
}
__device__ __forceinline__ float bb2f(ushortb u) {
    union { unsigned u; float f; } x; x.u = ((unsigned)u) << 16; return x.f;
}

// packed fp32x2 -> bf16x2 (low|high), RNE. gfx950 v_cvt_pk_bf16_f32 if available.
__device__ __forceinline__ unsigned pkbb(float a, float b) {
#if __has_builtin(__builtin_amdgcn_cvt_pk_bf16_f32)
    auto p = __builtin_amdgcn_cvt_pk_bf16_f32(a, b);
    unsigned u; __builtin_memcpy(&u, &p, 4);
    return u;
#else
    return (unsigned)f2bb(a) | ((unsigned)f2bb(b) << 16);
#endif
}

#if __has_builtin(__builtin_amdgcn_exp2f)
#define EXP2(x) __builtin_amdgcn_exp2f(x)
#else
#define EXP2(x) exp2f(x)
#endif

// async global->LDS DMA, 16B/lane; lds base wave-uniform, lane -> base+lane*16
__device__ __forceinline__ void async_ld16(void* lds, const void* g) {
    __builtin_amdgcn_global_load_lds(
        (const __attribute__((address_space(1))) void*)g,
        (__attribute__((address_space(3))) void*)lds, 16, 0, 0);
}

// ---------------------------------------------------------------------------
#define EP_EMB       0   // + bias + pe table
#define EP_RES       2   // + bf16 residual
#define EP_BIAS_RELU 3   // + bias, relu
#define EP_BIAS_RES  4   // + bias + bf16 residual
#define EP_QKV       7   // N=1536 fused: cols<1024 -> Qb/Kb, cols>=1024 -> Vt transposed

// C[M,N] = A[M,K] @ Bt[N,K]^T (+ epilogue). bf16 in, fp32 MFMA accum, bf16 out.
// Block 256 thr (4 waves 2x2), tile 128x128, BK=64, double-buffered
// global_load_lds staging; XOR-swizzled unpadded LDS. 64 KB LDS -> 2 blk/CU
// (cross-block overlap hides the per-tile barrier drain -- m114).
template <int EP>
__global__ __launch_bounds__(256) void gemm_mfma(
    const ushortb* __restrict__ A, const ushortb* __restrict__ Bt,
    const float* __restrict__ bias, const ushortb* __restrict__ res,
    const float* __restrict__ pe, ushortb* __restrict__ C,
    int M, int N, int K)
{
    __shared__ ushortb sA[2][128][64];   // 32 KB
    __shared__ ushortb sB[2][128][64];   // 32 KB

    const int tid = threadIdx.x;
    const int wave = tid >> 6, lane = tid & 63;
    const int quad = lane >> 4, l15 = lane & 15;
    const int row0 = blockIdx.x * 128;
    const int col0 = blockIdx.y * 128;
    const int wm = (wave >> 1) * 64, wn = (wave & 1) * 64;
    const int srl = lane >> 3, slot = lane & 7;

    f32x4 acc[4][4];
    #pragma unroll
    for (int i = 0; i < 4; ++i)
        #pragma unroll
        for (int j = 0; j < 4; ++j) acc[i][j] = (f32x4){0.f, 0.f, 0.f, 0.f};

    // initial stage -> buffer 0
    #pragma unroll
    for (int c = 0; c < 4; ++c) {
        int rbase = wave * 32 + c * 8;
        int r = rbase + srl;
        int ka = (slot ^ ((r ^ (r >> 3)) & 7)) * 8;
        async_ld16(&sA[0][rbase][0], A  + (size_t)(row0 + r) * K + ka);
        async_ld16(&sB[0][rbase][0], Bt + (size_t)(col0 + r) * K + ka);
    }

    int buf = 0;
    for (int k0 = 0; k0 < K; k0 += 64) {
        __syncthreads();   // drains DMA for 'buf' + prev compute
        if (k0 + 64 < K) {
            int nb = buf ^ 1;
            #pragma unroll
            for (int c = 0; c < 4; ++c) {
                int rbase = wave * 32 + c * 8;
                int r = rbase + srl;
                int ka = (slot ^ ((r ^ (r >> 3)) & 7)) * 8;
                async_ld16(&sA[nb][rbase][0], A  + (size_t)(row0 + r) * K + k0 + 64 + ka);
                async_ld16(&sB[nb][rbase][0], Bt + (size_t)(col0 + r) * K + k0 + 64 + ka);
            }
        }
        #pragma unroll
        for (int kc = 0; kc < 2; ++kc) {
            short8 af[4], bf[4];
            #pragma unroll
            for (int i = 0; i < 4; ++i) {
                int m = wm + i * 16 + l15;
                af[i] = *(const short8*)&sA[buf][m][(((kc * 4 + quad) ^ ((m ^ (m >> 3)) & 7))) * 8];
            }
            #pragma unroll
            for (int j = 0; j < 4; ++j) {
                int n = wn + j * 16 + l15;
                bf[j] = *(const short8*)&sB[buf][n][(((kc * 4 + quad) ^ ((n ^ (n >> 3)) & 7))) * 8];
            }
            #pragma unroll
            for (int i = 0; i < 4; ++i)
                #pragma unroll
                for (int j = 0; j < 4; ++j)
                    acc[i][j] = __builtin_amdgcn_mfma_f32_16x16x32_bf16(af[i], bf[j], acc[i][j], 0, 0, 0);
        }
        buf ^= 1;
    }

    #pragma unroll
    for (int i = 0; i < 4; ++i) {
        #pragma unroll
        for (int r = 0; r < 4; ++r) {
            int row = row0 + wm + i * 16 + quad * 4 + r;
            #pragma unroll
            for (int j = 0; j < 4; ++j) {
                int col = col0 + wn + j * 16 + l15;
                float v = acc[i][j][r];
                if constexpr (EP == EP_EMB) {
                    v += bias[col] + pe[((row & 1023) << 9) + col];
                } else if constexpr (EP == EP_RES) {
                    v += bb2f(res[(size_t)row * N + col]);
                } else if constexpr (EP == EP_BIAS_RELU) {
                    v = fmaxf(v + bias[col], 0.0f);
                } else if constexpr (EP == EP_BIAS_RES) {
                    v += bias[col] + bb2f(res[(size_t)row * N + col]);
                }
                C[(size_t)row * N + col] = f2bb(v);
            }
        }
    }
}

// ---------------------------------------------------------------------------
// QKV projection on a 128x256 tile, BK=32: halves A re-staging (x6 instead of
// x12 col-blocks) and cuts staged bytes 25%. 512 thr (8 waves, 2M x 4N), wave
// tile 64x64 (acc 64 f32 -> ~110 VGPR, no cap needed), 48 KB LDS -> 2 blk/CU
// at the 768-block grid (cross-block overlap retained). BK=32 swizzle math
// verified in round 5 (that run passed; its failure was a VGPR cap).
__global__ __launch_bounds__(512) void gemm_wide_qkv(
    const ushortb* __restrict__ A, const ushortb* __restrict__ Bt,
    ushortb* __restrict__ C, int M, int K)
{
    __shared__ ushortb sA[2][128][32];   // 16 KB
    __shared__ ushortb sB[2][256][32];   // 32 KB

    const int tid = threadIdx.x;
    const int wave = tid >> 6, lane = tid & 63;
    const int quad = lane >> 4, l15 = lane & 15;
    const int row0 = blockIdx.x * 128;
    const int col0 = blockIdx.y * 256;
    const int wm = (wave >> 2) * 64;     // 2 row groups of 64
    const int wn = (wave & 3) * 64;      // 4 col groups of 64
    const int r_in = lane >> 2, slot = lane & 3;   // 16 rows per wave-inst

    f32x4 acc[4][4];
    #pragma unroll
    for (int i = 0; i < 4; ++i)
        #pragma unroll
        for (int j = 0; j < 4; ++j) acc[i][j] = (f32x4){0.f, 0.f, 0.f, 0.f};

    // stage one 128x32 A-slab (1 inst/wave) + 256x32 B-slab (2 insts/wave)
    auto stage = [&](int nb, int k0) {
        {
            int rbase = wave * 16;
            int r = rbase + r_in;
            int ka = (slot ^ ((r ^ (r >> 2)) & 3)) * 8;
            async_ld16(&sA[nb][rbase][0], A + (size_t)(row0 + r) * K + k0 + ka);
        }
        #pragma unroll
        for (int c = 0; c < 2; ++c) {
            int rbase = c * 128 + wave * 16;
            int r = rbase + r_in;
            int ka = (slot ^ ((r ^ (r >> 2)) & 3)) * 8;
            async_ld16(&sB[nb][rbase][0], Bt + (size_t)(col0 + r) * K + k0 + ka);
        }
    };

    stage(0, 0);

    int buf = 0;
    for (int k0 = 0; k0 < K; k0 += 32) {
        __syncthreads();   // drains DMA for 'buf' + prev compute
        if (k0 + 32 < K) stage(buf ^ 1, k0 + 32);
        short8 af[4], bf[4];
        #pragma unroll
        for (int i = 0; i < 4; ++i) {
            int m = wm + i * 16 + l15;
            af[i] = *(const short8*)&sA[buf][m][(quad ^ ((m ^ (m >> 2)) & 3)) * 8];
        }
        #pragma unroll
        for (int j = 0; j < 4; ++j) {
            int n = wn + j * 16 + l15;
            bf[j] = *(const short8*)&sB[buf][n][(quad ^ ((n ^ (n >> 2)) & 3)) * 8];
        }
        #pragma unroll
        for (int i = 0; i < 4; ++i)
            #pragma unroll
            for (int j = 0; j < 4; ++j)
                acc[i][j] = __builtin_amdgcn_mfma_f32_16x16x32_bf16(af[i], bf[j], acc[i][j], 0, 0, 0);
        buf ^= 1;
    }

    // EP_QKV epilogue: col0 is 256-aligned so the Q/K vs V branch is uniform.
    if (col0 < 1024) {
        ushortb* dst = C + ((size_t)(col0 >> 9)) * ((size_t)M * 512);
        #pragma unroll
        for (int i = 0; i < 4; ++i)
            #pragma unroll
            for (int r = 0; r < 4; ++r) {
                int row = row0 + wm + i * 16 + quad * 4 + r;
                #pragma unroll
                for (int j = 0; j < 4; ++j) {
                    int col = (col0 + wn + j * 16 + l15) & 511;
                    dst[(size_t)row * 512 + col] = f2bb(acc[i][j][r]);
                }
            }
    } else {
        ushortb* Vt = C + (size_t)2 * M * 512;
        int bb_ = row0 >> 10;
        #pragma unroll
        for (int i = 0; i < 4; ++i) {
            int s = (row0 & 1023) + wm + i * 16 + quad * 4;
            #pragma unroll
            for (int j = 0; j < 4; ++j) {
                int vcol = col0 + wn + j * 16 + l15 - 1024;
                int h = vcol >> 7, e = vcol & 127;
                uint2 v;
                v.x = pkbb(acc[i][j][0], acc[i][j][1]);
                v.y = pkbb(acc[i][j][2], acc[i][j][3]);
                *(uint2*)&Vt[((size_t)((bb_ * 4 + h) * 128 + e) << 10) + s] = v;
            }
        }
    }
}

// ---------------------------------------------------------------------------
// 256x256-tile GEMM, BK=64, 2-phase __syncthreads structure, 128 KB LDS
// (1 blk/CU; 256^2 wave tile needs >128 VGPR so 2 blk/CU is infeasible --
// round-5 spill disaster). 512 thr (8 waves, 2M x 4N), wave tile 128x64.
// 0.375 ds_read/MFMA vs 0.5 on the 128^2 tile. Bias+ReLU epilogue (FFN1).
__global__ __launch_bounds__(512, 2) void gemm_256(
    const ushortb* __restrict__ A, const ushortb* __restrict__ Bt,
    const float* __restrict__ bias, ushortb* __restrict__ C,
    int M, int N, int K)
{
    __shared__ ushortb sA[2][256][64];   // 64 KB
    __shared__ ushortb sB[2][256][64];   // 64 KB

    const int tid = threadIdx.x;
    const int wave = tid >> 6, lane = tid & 63;
    const int quad = lane >> 4, l15 = lane & 15;
    const int row0 = blockIdx.x * 256;
    const int col0 = blockIdx.y * 256;
    const int wm = (wave >> 2) * 128;    // 2 row groups of 128
    const int wn = (wave & 3) * 64;      // 4 col groups of 64
    const int srl = lane >> 3, slot = lane & 7;

    f32x4 acc[8][4];
    #pragma unroll
    for (int i = 0; i < 8; ++i)
        #pragma unroll
        for (int j = 0; j < 4; ++j) acc[i][j] = (f32x4){0.f, 0.f, 0.f, 0.f};

    // initial stage -> buffer 0 (per wave: rows wave*32..wave*32+31 of A and B)
    #pragma unroll
    for (int c = 0; c < 4; ++c) {
        int rbase = wave * 32 + c * 8;
        int r = rbase + srl;
        int ka = (slot ^ ((r ^ (r >> 3)) & 7)) * 8;
        async_ld16(&sA[0][rbase][0], A  + (size_t)(row0 + r) * K + ka);
        async_ld16(&sB[0][rbase][0], Bt + (size_t)(col0 + r) * K + ka);
    }

    int buf = 0;
    for (int k0 = 0; k0 < K; k0 += 64) {
        __syncthreads();   // drains DMA for 'buf' + prev compute
        if (k0 + 64 < K) {
            int nb = buf ^ 1;
            #pragma unroll
            for (int c = 0; c < 4; ++c) {
                int rbase = wave * 32 + c * 8;
                int r = rbase + srl;
                int ka = (slot ^ ((r ^ (r >> 3)) & 7)) * 8;
                async_ld16(&sA[nb][rbase][0], A  + (size_t)(row0 + r) * K + k0 + 64 + ka);
                async_ld16(&sB[nb][rbase][0], Bt + (size_t)(col0 + r) * K + k0 + 64 + ka);
            }
        }
        #pragma unroll
        for (int kc = 0; kc < 2; ++kc) {
            short8 af[8], bf[4];
            #pragma unroll
            for (int i = 0; i < 8; ++i) {
                int m = wm + i * 16 + l15;
                af[i] = *(const short8*)&sA[buf][m][(((kc * 4 + quad) ^ ((m ^ (m >> 3)) & 7))) * 8];
            }
            #pragma unroll
            for (int j = 0; j < 4; ++j) {
                int n = wn + j * 16 + l15;
                bf[j] = *(const short8*)&sB[buf][n][(((kc * 4 + quad) ^ ((n ^ (n >> 3)) & 7))) * 8];
            }
            #pragma unroll
            for (int i = 0; i < 8; ++i)
                #pragma unroll
                for (int j = 0; j < 4; ++j)
                    acc[i][j] = __builtin_amdgcn_mfma_f32_16x16x32_bf16(af[i], bf[j], acc[i][j], 0, 0, 0);
        }
        buf ^= 1;
    }

    #pragma unroll
    for (int i = 0; i < 8; ++i) {
        #pragma unroll
        for (int r = 0; r < 4; ++r) {
            int row = row0 + wm + i * 16 + quad * 4 + r;
            #pragma unroll
            for (int j = 0; j < 4; ++j) {
                int col = col0 + wn + j * 16 + l15;
                float v = fmaxf(acc[i][j][r] + bias[col], 0.0f);
                C[(size_t)row * N + col] = f2bb(v);
            }
        }
    }
}

// ---------------------------------------------------------------------------
// Merged prep kernel: all six independent prep stages in one dispatch over a
// partitioned 1D grid (block-uniform branch). Saves launch gaps + tails.
// Block 8192 additionally zeros the zbuf accumulators + done-counter (33 u32).
//   [0,8192)        conv_x: x fp32 -> xb bf16 (4 elems/thread)
//   [8192,10240)    pe table fp32 [1024][512]
//   [10240,10368)   pairT512: emb_w (z=0) / WO (z=1) transpose, 8x8x2
//   [10368,10560)   qkvT: WQ/WK/WV [512][128] -> wqkvt rows, 2x8x12, Q scaled
//   [10560,10816)   tileT l1w [512][2048] -> l1wt, 32x8
//   [10816,11072)   tileT l2w [2048][512] -> l2wt, 8x32
__global__ __launch_bounds__(256) void prep_all(
    const float* __restrict__ x, ushortb* __restrict__ xb,
    float* __restrict__ pe,
    const float* __restrict__ emb_w, const float* __restrict__ WO,
    ushortb* __restrict__ embwt, ushortb* __restrict__ wot,
    const float* __restrict__ WQ, const float* __restrict__ WK,
    const float* __restrict__ WV, ushortb* __restrict__ wqkvt, float qscale,
    const float* __restrict__ l1w, ushortb* __restrict__ l1wt,
    const float* __restrict__ l2w, ushortb* __restrict__ l2wt,
    unsigned* __restrict__ zinit)
{
    __shared__ float t[64][65];
    const int bid = blockIdx.x;
    const int tid = threadIdx.x;

    if (bid < 8192) {                       // conv_x
        size_t i4 = (size_t)bid * 256 + tid;
        float4 v = *(const float4*)(x + i4 * 4);
        ushort4 o;
        o.x = f2bb(v.x); o.y = f2bb(v.y); o.z = f2bb(v.z); o.w = f2bb(v.w);
        *(ushort4*)(xb + i4 * 4) = o;
        return;
    }
    if (bid < 10240) {                      // pe table (+ zbuf/counter zero)
        if (bid == 8192 && tid < 33) zinit[tid] = 0u;
        int idx = (bid - 8192) * 256 + tid;  // s*512 + c
        int s = idx >> 9, c = idx & 511;
        float div = expf((float)(c & ~1) * (-9.210340371976184f / 512.0f));
        float ang = (float)s * div;
        pe[idx] = (c & 1) ? cosf(ang) : sinf(ang);
        return;
    }

    const int tx = tid & 63, ty = tid >> 6;

    if (bid < 10368) {                      // pairT512 (8x8x2)
        int b2 = bid - 10240;
        int c0 = (b2 & 7) * 64, r0 = ((b2 >> 3) & 7) * 64, z = b2 >> 6;
        const float* in = z ? WO : emb_w;
        ushortb* out = z ? wot : embwt;
        #pragma unroll
        for (int i = 0; i < 16; ++i) {
            int r = ty + i * 4;
            t[r][tx] = in[(size_t)(r0 + r) * 512 + c0 + tx];
        }
        __syncthreads();
        #pragma unroll
        for (int i = 0; i < 16; ++i) {
            int r = ty + i * 4;
            out[(size_t)(c0 + r) * 512 + r0 + tx] = f2bb(t[tx][r]);
        }
        return;
    }
    if (bid < 10560) {                      // qkvT (2x8x12)
        int b3 = bid - 10368;
        int c0 = (b3 & 1) * 64, r0 = ((b3 >> 1) & 7) * 64, z = b3 >> 4;
        int sel = z >> 2, zz = z & 3;
        const float* in = (sel == 0 ? WQ : (sel == 1 ? WK : WV)) + (size_t)zz * 65536;
        ushortb* out = wqkvt + (size_t)sel * 262144 + (size_t)zz * 65536;
        const float scale = (sel == 0) ? qscale : 1.0f;
        #pragma unroll
        for (int i = 0; i < 16; ++i) {
            int r = ty + i * 4;
            t[r][tx] = in[(size_t)(r0 + r) * 128 + c0 + tx] * scale;
        }
        __syncthreads();
        #pragma unroll
        for (int i = 0; i < 16; ++i) {
            int r = ty + i * 4;
            out[(size_t)(c0 + r) * 512 + r0 + tx] = f2bb(t[tx][r]);
        }
        return;
    }
    if (bid < 10816) {                      // tileT l1w: [512][2048] -> [2048][512]
        int b4 = bid - 10560;
        int c0 = (b4 & 31) * 64, r0 = (b4 >> 5) * 64;
        #pragma unroll
        for (int i = 0; i < 16; ++i) {
            int r = ty + i * 4;
            t[r][tx] = l1w[(size_t)(r0 + r) * 2048 + c0 + tx];
        }
        __syncthreads();
        #pragma unroll
        for (int i = 0; i < 16; ++i) {
            int r = ty + i * 4;
            l1wt[(size_t)(c0 + r) * 512 + r0 + tx] = f2bb(t[tx][r]);
        }
        return;
    }
    {                                       // tileT l2w: [2048][512] -> [512][2048]
        int b5 = bid - 10816;
        int c0 = (b5 & 7) * 64, r0 = (b5 >> 3) * 64;
        #pragma unroll
        for (int i = 0; i < 16; ++i) {
            int r = ty + i * 4;
            t[r][tx] = l2w[(size_t)(r0 + r) * 512 + c0 + tx];
        }
        __syncthreads();
        #pragma unroll
        for (int i = 0; i < 16; ++i) {
            int r = ty + i * 4;
            l2wt[(size_t)(c0 + r) * 2048 + r0 + tx] = f2bb(t[tx][r]);
        }
        return;
    }
}

// ---------------------------------------------------------------------------
// MFMA flash attention, fixed-max softmax, double-buffered DMA K/V staging,
// XCD-local grid, packed bf16 conversions. Q pre-scaled by log2(e)/sqrt(128).
// Round-0 structure (__syncthreads double-buffer) with PAIRED staging:
// each sync period stages TWO 32-wide K/V tiles (sub-buffers, inner layouts
// unchanged) and runs the tile body twice -> 16 barrier drains instead of 32.
// NO setprio (round-8 A/B: lockstep-barrier regime, setprio cost ~6.6 us).
__global__ __launch_bounds__(256) void attn_mfma(
    const ushortb* __restrict__ Qb, const ushortb* __restrict__ Kb,
    const ushortb* __restrict__ Vt, ushortb* __restrict__ O)
{
    __shared__ ushortb sK[2][2][32][128];    // 32 KB
    __shared__ ushortb sVt[2][2][128][32];   // 32 KB
    __shared__ ushortb sP[4][32][40];        // 10 KB, [wave][q_local][t]

    const int tid = threadIdx.x;
    const int wave = tid >> 6, lane = tid & 63;
    const int quad = lane >> 4, l15 = lane & 15;
    const int bid = blockIdx.x;          // XCD swizzle: same (b,h) -> ids 64 apart
    const int bh = bid & 63, qc = bid >> 6;
    const int b = bh >> 2, h = bh & 3;
    const int q0 = qc * 128 + wave * 32;
    const size_t qk_off = ((size_t)b << 10) * 512 + h * 128;
    const ushortb* Qp = Qb + qk_off;
    const ushortb* Kp = Kb + qk_off;
    const ushortb* Vp = Vt + (((size_t)(b * 4 + h)) << 17);

    short8 qfA[4], qfB[4];   // B-frags: Q[q=l15 | 16+l15][k=quad*8+j]
    {
        const ushortb* qa = Qp + (size_t)(q0 + l15) * 512;
        const ushortb* qb = Qp + (size_t)(q0 + 16 + l15) * 512;
        #pragma unroll
        for (int kc = 0; kc < 4; ++kc) {
            qfA[kc] = *(const short8*)(qa + kc * 32 + quad * 8);
            qfB[kc] = *(const short8*)(qb + kc * 32 + quad * 8);
        }
    }

    f32x4 oA[8], oB[8];
    #pragma unroll
    for (int dt = 0; dt < 8; ++dt) {
        oA[dt] = (f32x4){0.f, 0.f, 0.f, 0.f};
        oB[dt] = (f32x4){0.f, 0.f, 0.f, 0.f};
    }
    float lA = 0.f, lB = 0.f;

    // initial stage: pair of tiles (t=0,32) -> buffer 0
    #pragma unroll
    for (int s = 0; s < 2; ++s) {
        #pragma unroll
        for (int c = 0; c < 2; ++c) {
            int seg = wave * 2 + c;
            int rk = seg * 4 + (lane >> 4);
            int ck = (lane & 15) ^ (rk & 15);
            async_ld16(&sK[0][s][seg * 4][0], Kp + (size_t)(s * 32 + rk) * 512 + ck * 8);
            int dv = seg * 16 + (lane >> 2);
            int cv = (lane & 3) ^ (dv & 3);
            async_ld16(&sVt[0][s][seg * 16][0], Vp + ((size_t)dv << 10) + s * 32 + cv * 8);
        }
    }

    int buf = 0;
    for (int t0 = 0; t0 < 1024; t0 += 64) {
        __syncthreads();   // DMA for 'buf' (both subs) complete + prev compute done
        if (t0 + 64 < 1024) {
            int nb = buf ^ 1;
            #pragma unroll
            for (int s = 0; s < 2; ++s) {
                #pragma unroll
                for (int c = 0; c < 2; ++c) {
                    int seg = wave * 2 + c;
                    int rk = seg * 4 + (lane >> 4);
                    int ck = (lane & 15) ^ (rk & 15);
                    async_ld16(&sK[nb][s][seg * 4][0],
                               Kp + (size_t)(t0 + 64 + s * 32 + rk) * 512 + ck * 8);
                    int dv = seg * 16 + (lane >> 2);
                    int cv = (lane & 3) ^ (dv & 3);
                    async_ld16(&sVt[nb][s][seg * 16][0],
                               Vp + ((size_t)dv << 10) + t0 + 64 + s * 32 + cv * 8);
                }
            }
        }

        #pragma unroll
        for (int sub = 0; sub < 2; ++sub) {
            // S^T: D[t][q]; t = quad*4+reg (+0/16), q = l15 (A-group) / 16+l15 (B)
            f32x4 sA0 = {0,0,0,0}, sA1 = {0,0,0,0}, sB0 = {0,0,0,0}, sB1 = {0,0,0,0};
            #pragma unroll
            for (int kc = 0; kc < 4; ++kc) {
                short8 k0f = *(const short8*)&sK[buf][sub][l15][((kc * 4 + quad) ^ l15) * 8];
                short8 k1f = *(const short8*)&sK[buf][sub][16 + l15][((kc * 4 + quad) ^ l15) * 8];
                sA0 = __builtin_amdgcn_mfma_f32_16x16x32_bf16(k0f, qfA[kc], sA0, 0, 0, 0);
                sA1 = __builtin_amdgcn_mfma_f32_16x16x32_bf16(k1f, qfA[kc], sA1, 0, 0, 0);
                sB0 = __builtin_amdgcn_mfma_f32_16x16x32_bf16(k0f, qfB[kc], sB0, 0, 0, 0);
                sB1 = __builtin_amdgcn_mfma_f32_16x16x32_bf16(k1f, qfB[kc], sB1, 0, 0, 0);
            }

            // fixed-max softmax: p = 2^score (log2e baked into Q scale)
            float pA0[4], pA1[4], pB0[4], pB1[4];
            float sumA = 0.f, sumB = 0.f;
            #pragma unroll
            for (int r = 0; r < 4; ++r) {
                pA0[r] = EXP2(sA0[r]); pA1[r] = EXP2(sA1[r]);
                pB0[r] = EXP2(sB0[r]); pB1[r] = EXP2(sB1[r]);
                sumA += pA0[r] + pA1[r];
                sumB += pB0[r] + pB1[r];
            }
            lA += sumA; lB += sumB;

            // store P[q][t] bf16 via packed converts (2 x uint2 per q-row half)
            uint2 w;
            w.x = pkbb(pA0[0], pA0[1]); w.y = pkbb(pA0[2], pA0[3]);
            *(uint2*)&sP[wave][l15][quad * 4] = w;
            w.x = pkbb(pA1[0], pA1[1]); w.y = pkbb(pA1[2], pA1[3]);
            *(uint2*)&sP[wave][l15][16 + quad * 4] = w;
            w.x = pkbb(pB0[0], pB0[1]); w.y = pkbb(pB0[2], pB0[3]);
            *(uint2*)&sP[wave][16 + l15][quad * 4] = w;
            w.x = pkbb(pB1[0], pB1[1]); w.y = pkbb(pB1[2], pB1[3]);
            *(uint2*)&sP[wave][16 + l15][16 + quad * 4] = w;

            short8 pfA = *(const short8*)&sP[wave][l15][quad * 8];
            short8 pfB = *(const short8*)&sP[wave][16 + l15][quad * 8];

            #pragma unroll
            for (int dt = 0; dt < 8; ++dt) {
                int d = dt * 16 + l15;
                short8 vfrag = *(const short8*)&sVt[buf][sub][d][(quad ^ (d & 3)) * 8];
                oA[dt] = __builtin_amdgcn_mfma_f32_16x16x32_bf16(pfA, vfrag, oA[dt], 0, 0, 0);
                oB[dt] = __builtin_amdgcn_mfma_f32_16x16x32_bf16(pfB, vfrag, oB[dt], 0, 0, 0);
            }
        }
        buf ^= 1;
    }

    lA += __shfl_xor(lA, 16); lA += __shfl_xor(lA, 32);
    lB += __shfl_xor(lB, 16); lB += __shfl_xor(lB, 32);

    const size_t obase = (((size_t)(b * 4 + h) << 10) + q0) << 7;
    #pragma unroll
    for (int r = 0; r < 4; ++r) {
        float invA = 1.0f / __shfl(lA, quad * 4 + r);
        float invB = 1.0f / __shfl(lB, quad * 4 + r);
        int qa = quad * 4 + r, qb = 16 + quad * 4 + r;
        #pragma unroll
        for (int dt = 0; dt < 8; ++dt) {
            O[obase + ((size_t)qa << 7) + dt * 16 + l15] = f2bb(oA[dt][r] * invA);
            O[obase + ((size_t)qb << 7) + dt * 16 + l15] = f2bb(oB[dt][r] * invB);
        }
    }
}

// ---------------------------------------------------------------------------
// LayerNorm over 512 features: wave per row, 8 elems/lane, shuffle reduce.
__global__ __launch_bounds__(256) void ln_kernel(const ushortb* __restrict__ in,
                                                 const float* __restrict__ g,
                                                 const float* __restrict__ bta,
                                                 ushortb* __restrict__ out)
{
    const int lane = threadIdx.x & 63, w = threadIdx.x >> 6;
    const size_t row = (size_t)blockIdx.x * 4 + w;
    const int e0 = lane * 8;
    short8 v8 = *(const short8*)(in + row * 512 + e0);
    float v[8];
    #pragma unroll
    for (int k = 0; k < 8; ++k) v[k] = bb2f((ushortb)((short*)&v8)[k]);
    float s = 0.f, sq = 0.f;
    #pragma unroll
    for (int k = 0; k < 8; ++k) { s += v[k]; sq += v[k] * v[k]; }
    #pragma unroll
    for (int o = 1; o < 64; o <<= 1) { s += __shfl_xor(s, o); sq += __shfl_xor(sq, o); }
    float mu = s * (1.0f / 512.0f);
    float var = sq * (1.0f / 512.0f) - mu * mu;
    float rstd = rsqrtf(var + 1e-5f);
    float4 g0 = *(const float4*)(g + e0),  g1 = *(const float4*)(g + e0 + 4);
    float4 b0 = *(const float4*)(bta + e0), b1 = *(const float4*)(bta + e0 + 4);
    float gg[8] = {g0.x, g0.y, g0.z, g0.w, g1.x, g1.y, g1.z, g1.w};
    float bb[8] = {b0.x, b0.y, b0.z, b0.w, b1.x, b1.y, b1.z, b1.w};
    short8 o8;
    #pragma unroll
    for (int k = 0; k < 8; ++k)
        ((short*)&o8)[k] = (short)f2bb((v[k] - mu) * rstd * gg[k] + bb[k]);
    *(short8*)(out + row * 512 + e0) = o8;
}

// ---------------------------------------------------------------------------
// MaxPool1d(16) + FC[32768,2] + log_softmax fused: grid (16 batch, 16 chunks),
// atomicAdd partials into zbuf; last block (device-scope ticket) computes the
// logits. done counter sits at zbuf+32 (both zeroed by prep_all each run).
__global__ __launch_bounds__(256) void final_fused(const ushortb* __restrict__ ln2,
                                                   const float* __restrict__ fcw,
                                                   const float* __restrict__ fcb,
                                                   float* __restrict__ zbuf,
                                                   unsigned* __restrict__ done,
                                                   float* __restrict__ out)
{
    const int b = blockIdx.x, chunk = blockIdx.y;
    const int tid = threadIdx.x;
    float a0 = 0.0f, a1 = 0.0f;
    #pragma unroll
    for (int t = 0; t < 8; ++t) {
        int m = chunk * 2048 + t * 256 + tid;
        int s = m >> 5, j = m & 31;
        const ushortb* p = ln2 + (((size_t)(b * 1024 + s)) << 9) + j * 16;
        float mx = -1e30f;
        #pragma unroll
        for (int e = 0; e < 16; ++e) mx = fmaxf(mx, bb2f(p[e]));
        a0 += mx * fcw[2 * m];
        a1 += mx * fcw[2 * m + 1];
    }
    __shared__ float r0[256], r1[256];
    __shared__ unsigned lastf;
    r0[tid] = a0; r1[tid] = a1;
    __syncthreads();
    for (int o = 128; o > 0; o >>= 1) {
        if (tid < o) { r0[tid] += r0[tid + o]; r1[tid] += r1[tid + o]; }
        __syncthreads();
    }
    if (tid == 0) {
        atomicAdd(&zbuf[2 * b],     r0[0]);
        atomicAdd(&zbuf[2 * b + 1], r1[0]);
        __threadfence();                       // order partials before ticket
        lastf = (atomicAdd(done, 1u) == 255u); // 256 blocks total
    }
    __syncthreads();
    if (lastf && tid < 16) {
        __threadfence();
        // coherent reads of all partials via device-scope atomic no-ops
        float z0 = atomicAdd(&zbuf[2 * tid], 0.0f)     + fcb[0];
        float z1 = atomicAdd(&zbuf[2 * tid + 1], 0.0f) + fcb[1];
        float mx = fmaxf(z0, z1);
        float lse = mx + logf(expf(z0 - mx) + expf(z1 - mx));
        out[2 * tid]     = z0 - lse;
        out[2 * tid + 1] = z1 - lse;
    }
}

// ---------------------------------------------------------------------------
extern "C" void kernel_launch(void* const* d_in, const int* in_sizes, int n_in,
                              void* d_out, int out_size, void* d_ws, size_t ws_size,
                              hipStream_t stream)
{
    const float* x     = (const float*)d_in[0];
    const float* emb_w = (const float*)d_in[1];
    const float* emb_b = (const float*)d_in[2];
    const float* WQ    = (const float*)d_in[3];
    const float* WK    = (const float*)d_in[4];
    const float* WV    = (const float*)d_in[5];
    const float* WO    = (const float*)d_in[6];
    const float* g1    = (const float*)d_in[7];
    const float* b1    = (const float*)d_in[8];
    const float* l1w   = (const float*)d_in[9];
    const float* l1b   = (const float*)d_in[10];
    const float* l2w   = (const float*)d_in[11];
    const float* l2b   = (const float*)d_in[12];
    const float* g2    = (const float*)d_in[13];
    const float* b2    = (const float*)d_in[14];
    const float* fcw   = (const float*)d_in[15];
    const float* fcb   = (const float*)d_in[16];
    float* out = (float*)d_out;

    char* ws = (char*)d_ws;
    const size_t Ub = (size_t)16384 * 512 * 2;   // 16.78 MB bf16 activation unit
    // u0: xb -> r1 -> r2   u1: h0b -> ln2   u2: Qb -> ln1
    // u3: Kb -> mid[0]     u4: Vt -> mid[1] u5: headR -> mid[2]  u6: mid[3]
    ushortb* xb    = (ushortb*)(ws + 0 * Ub);
    ushortb* h0b   = (ushortb*)(ws + 1 * Ub);
    ushortb* Qb    = (ushortb*)(ws + 2 * Ub);   // Kb = Qb + M*512, Vt = Qb + 2*M*512
    ushortb* Kb    = (ushortb*)(ws + 3 * Ub);
    ushortb* Vt    = (ushortb*)(ws + 4 * Ub);
    ushortb* headR = (ushortb*)(ws + 5 * Ub);
    ushortb* mid   = (ushortb*)(ws + 3 * Ub);   // [16384,2048] over u3..u6
    ushortb* r1    = xb;
    ushortb* ln1   = Qb;
    ushortb* r2    = xb;
    ushortb* ln2   = h0b;
    char* wb = ws + 7 * Ub;
    ushortb* embwt = (ushortb*)(wb);                        // [512][512]
    ushortb* wqkvt = (ushortb*)(wb + 524288);               // [1536][512]
    ushortb* wot   = (ushortb*)(wb + 2097152);              // [512][512]
    ushortb* l1wt  = (ushortb*)(wb + 2621440);              // [2048][512]
    ushortb* l2wt  = (ushortb*)(wb + 4718592);              // [512][2048]
    float*   pe    = (float*)  (wb + 6815744);              // [1024][512] fp32
    float*   zbuf  = (float*)  (wb + 8912896);              // [16][2] + counter
    unsigned* done = (unsigned*)(zbuf + 32);

    const int M = 16384;
    const float qscale = 0.12753139626997592f;  // log2(e)/sqrt(128)

    // prep: one merged dispatch (includes zbuf/done zeroing)
    prep_all<<<11072, 256, 0, stream>>>(
        x, xb, pe, emb_w, WO, embwt, wot,
        WQ, WK, WV, wqkvt, qscale, l1w, l1wt, l2w, l2wt,
        (unsigned*)zbuf);

    // 1) h0 = x @ emb_w + emb_b + pe
    gemm_mfma<EP_EMB><<<dim3(M / 128, 4), 256, 0, stream>>>(
        xb, embwt, emb_b, nullptr, pe, h0b, M, 512, 512);

    // 2) fused QKV projection on the 128x256/BK=32 kernel (A re-staged x6
    //    instead of x12; 768 blocks -> 2 blk/CU overlap retained)
    gemm_wide_qkv<<<dim3(M / 128, 6), 512, 0, stream>>>(
        h0b, wqkvt, Qb, M, 512);

    // 3) flash attention -> headR bf16 ([B,H,S,DK] flat == raw reshape)
    attn_mfma<<<512, 256, 0, stream>>>(Qb, Kb, Vt, headR);

    // 4) r1 = headR @ WO + h0 ; ln1 = LN(r1)
    gemm_mfma<EP_RES><<<dim3(M / 128, 4), 256, 0, stream>>>(
        headR, wot, nullptr, h0b, nullptr, r1, M, 512, 512);
    ln_kernel<<<M / 4, 256, 0, stream>>>(r1, g1, b1, ln1);

    // 5) FFN: 256^2-BK64 up-proj (grid 64x8 = 512 blocks), 128^2 down-proj
    gemm_256<<<dim3(M / 256, 8), 512, 0, stream>>>(
        ln1, l1wt, l1b, mid, M, 2048, 512);
    gemm_mfma<EP_BIAS_RES><<<dim3(M / 128, 4), 256, 0, stream>>>(
        mid, l2wt, l2b, ln1, nullptr, r2, M, 512, 2048);
    ln_kernel<<<M / 4, 256, 0, stream>>>(r2, g2, b2, ln2);

    // 6) maxpool + FC + log_softmax (single fused dispatch, last-block logits)
    final_fused<<<dim3(16, 16), 256, 0, stream>>>(ln2, fcw, fcb, zbuf, done, out);
}